// Round 1
// baseline (1042.858 us; speedup 1.0000x reference)
//
#include <hip/hip_runtime.h>
#include <math.h>

#define NB    2
#define NQ    900
#define NKV   4096
#define DIMM  256
#define NHEAD 8
#define HD    32
#define RPEH  512
#define GRID  64
#define QB    16
#define KB    64

// ---------------------------------------------------------------------------
// C[m][n] = (sum_k A[m][k] * W[n][k] + bias[n]) * scale
// A: (M,K) row-major, W: (N,K) row-major. N,K multiples of 32. M guarded.
// Block: 256 threads -> 32x32 output tile, 2x2 micro-tile per thread.
// ---------------------------------------------------------------------------
__global__ __launch_bounds__(256) void gemm_bias_kernel(
    const float* __restrict__ A, const float* __restrict__ W,
    const float* __restrict__ bias, float* __restrict__ C,
    int M, int N, int K, float scale)
{
    __shared__ float As[32][33];
    __shared__ float Ws[32][33];
    const int t  = threadIdx.x;
    const int tr = t >> 4;        // 0..15
    const int tc = t & 15;        // 0..15
    const int brow = blockIdx.y * 32;
    const int bcol = blockIdx.x * 32;
    float acc00 = 0.f, acc01 = 0.f, acc10 = 0.f, acc11 = 0.f;

    for (int kt = 0; kt < K; kt += 32) {
        #pragma unroll
        for (int i = 0; i < 4; ++i) {
            int idx = t + i * 256;
            int r = idx >> 5, c = idx & 31;
            int gr = brow + r;
            As[r][c] = (gr < M) ? A[gr * K + kt + c] : 0.f;
            Ws[r][c] = W[(bcol + r) * K + kt + c];
        }
        __syncthreads();
        #pragma unroll 8
        for (int k = 0; k < 32; ++k) {
            float a0 = As[tr * 2][k], a1 = As[tr * 2 + 1][k];
            float w0 = Ws[tc * 2][k], w1 = Ws[tc * 2 + 1][k];
            acc00 += a0 * w0; acc01 += a0 * w1;
            acc10 += a1 * w0; acc11 += a1 * w1;
        }
        __syncthreads();
    }
    int gc0 = bcol + tc * 2, gc1 = gc0 + 1;
    int gr0 = brow + tr * 2, gr1 = gr0 + 1;
    if (gr0 < M) {
        C[gr0 * N + gc0] = (acc00 + bias[gc0]) * scale;
        C[gr0 * N + gc1] = (acc01 + bias[gc1]) * scale;
    }
    if (gr1 < M) {
        C[gr1 * N + gc0] = (acc10 + bias[gc0]) * scale;
        C[gr1 * N + gc1] = (acc11 + bias[gc1]) * scale;
    }
}

// ---------------------------------------------------------------------------
// RPE: one block per (b,q). Computes rpe_x[64][8], rpe_y[64][8], stored
// transposed as [bq][h][64] for coalesced reload in attention.
// ---------------------------------------------------------------------------
__global__ __launch_bounds__(256) void rpe_kernel(
    const float* __restrict__ ref_pts,   // (B*Q, 4)
    const float* __restrict__ w1x, const float* __restrict__ b1x,
    const float* __restrict__ w2x,       // (8,512)
    const float* __restrict__ w1y, const float* __restrict__ b1y,
    const float* __restrict__ w2y,
    float* __restrict__ rpex,            // (B*Q, 8, 64)
    float* __restrict__ rpey)
{
    __shared__ float sw1[2][RPEH][2];
    __shared__ float sb1[2][RPEH];
    __shared__ float sw2[2][NHEAD][RPEH];
    const int t = threadIdx.x;
    for (int i = t; i < RPEH * 2; i += 256) {
        sw1[0][i >> 1][i & 1] = w1x[i];
        sw1[1][i >> 1][i & 1] = w1y[i];
    }
    for (int i = t; i < RPEH; i += 256) {
        sb1[0][i] = b1x[i];
        sb1[1][i] = b1y[i];
    }
    for (int i = t; i < NHEAD * RPEH; i += 256) {
        sw2[0][i >> 9][i & 511] = w2x[i];
        sw2[1][i >> 9][i & 511] = w2y[i];
    }
    const int bq = blockIdx.x;
    const float cx = ref_pts[bq * 4 + 0];
    const float cy = ref_pts[bq * 4 + 1];
    const float sw = ref_pts[bq * 4 + 2];
    const float sh = ref_pts[bq * 4 + 3];
    const float xl = (cx - sw * 0.5f) * 1024.f;
    const float xh = (cx + sw * 0.5f) * 1024.f;
    const float yl = (cy - sh * 0.5f) * 1024.f;
    const float yh = (cy + sh * 0.5f) * 1024.f;
    __syncthreads();

    const int pos  = t >> 1;     // 0..127
    const int half = t & 1;      // r-range split
    const int m    = pos >> 6;   // 0: x-mlp, 1: y-mlp
    const int i    = pos & 63;   // grid index
    const float p  = (i + 0.5f) * 16.f;
    const float d0 = (m == 0 ? xl : yl) - p;
    const float d1 = (m == 0 ? xh : yh) - p;

    float acc[NHEAD] = {};
    const int r0 = half * 256;
    for (int r = r0; r < r0 + 256; ++r) {
        float hdn = fmaxf(sw1[m][r][0] * d0 + sw1[m][r][1] * d1 + sb1[m][r], 0.f);
        #pragma unroll
        for (int h = 0; h < NHEAD; ++h) acc[h] += sw2[m][h][r] * hdn;
    }
    #pragma unroll
    for (int h = 0; h < NHEAD; ++h) acc[h] += __shfl_xor(acc[h], 1);
    if (half == 0) {
        float* outp = (m == 0 ? rpex : rpey) + bq * (NHEAD * GRID) + i;
        #pragma unroll
        for (int h = 0; h < NHEAD; ++h) outp[h * GRID] = acc[h];
    }
}

// ---------------------------------------------------------------------------
// Flash-style attention. Block = (q-tile of 16, head, batch). fp32.
// score = q.k + rpe_x[x] + rpe_y[y] - 100*mask, k index = y*64 + x.
// ---------------------------------------------------------------------------
__global__ __launch_bounds__(256) void attn_kernel(
    const float* __restrict__ Qp,    // (B*Q, 256), pre-scaled
    const float* __restrict__ Kp,    // (B*KV, 256)
    const float* __restrict__ Vp,
    const float* __restrict__ rpex,  // (B*Q, 8, 64)
    const float* __restrict__ rpey,
    const int*   __restrict__ mask,  // (B, KV)
    float* __restrict__ CTX)         // (B*Q, 256)
{
    __shared__ float qs[QB][33];
    __shared__ float ks[KB][33];
    __shared__ float vs[KB][33];
    __shared__ float rx[QB][GRID];
    __shared__ float ry[QB][GRID];
    __shared__ float sc[QB][KB + 1];
    __shared__ float fq[QB];
    __shared__ float lq[QB];
    __shared__ float mtile[KB];

    const int qt = blockIdx.x;
    const int h  = blockIdx.y;
    const int b  = blockIdx.z;
    const int q0 = qt * QB;
    const int t  = threadIdx.x;

    for (int idx = t; idx < QB * HD; idx += 256) {
        int qi = idx >> 5, d = idx & 31;
        int gq = q0 + qi;
        qs[qi][d] = (gq < NQ) ? Qp[(b * NQ + gq) * DIMM + h * HD + d] : 0.f;
    }
    for (int idx = t; idx < QB * GRID; idx += 256) {
        int qi = idx >> 6, x = idx & 63;
        int gq = q0 + qi;
        int base = (b * NQ + gq) * (NHEAD * GRID) + h * GRID + x;
        rx[qi][x] = (gq < NQ) ? rpex[base] : 0.f;
        ry[qi][x] = (gq < NQ) ? rpey[base] : 0.f;
    }

    float m_run = -1e30f, l_run = 0.f;
    const int oqi = t >> 4;
    const int od  = (t & 15) * 2;
    float oacc0 = 0.f, oacc1 = 0.f;
    __syncthreads();

    for (int kv0 = 0; kv0 < NKV; kv0 += KB) {
        for (int idx = t; idx < KB * HD; idx += 256) {
            int kj = idx >> 5, d = idx & 31;
            int g = (b * NKV + kv0 + kj) * DIMM + h * HD + d;
            ks[kj][d] = Kp[g];
            vs[kj][d] = Vp[g];
        }
        if (t < KB) mtile[t] = (float)mask[b * NKV + kv0 + t] * -100.f;
        __syncthreads();

        #pragma unroll
        for (int ii = 0; ii < (QB * KB) / 256; ++ii) {
            int s  = t + ii * 256;
            int qi = s & (QB - 1);
            int kj = s >> 4;
            float acc = 0.f;
            #pragma unroll 8
            for (int d = 0; d < HD; ++d) acc += qs[qi][d] * ks[kj][d];
            int gk = kv0 + kj;
            sc[qi][kj] = acc + rx[qi][gk & 63] + ry[qi][gk >> 6] + mtile[kj];
        }
        __syncthreads();

        if (t < QB) {
            float tmax = -1e30f;
            for (int kj = 0; kj < KB; ++kj) tmax = fmaxf(tmax, sc[t][kj]);
            float newm = fmaxf(m_run, tmax);
            float f = __expf(m_run - newm);
            float lsum = 0.f;
            for (int kj = 0; kj < KB; ++kj) {
                float pv = __expf(sc[t][kj] - newm);
                sc[t][kj] = pv;
                lsum += pv;
            }
            l_run = l_run * f + lsum;
            m_run = newm;
            fq[t] = f;
        }
        __syncthreads();

        float f = fq[oqi];
        float a0 = 0.f, a1 = 0.f;
        #pragma unroll 8
        for (int kj = 0; kj < KB; ++kj) {
            float pv = sc[oqi][kj];
            a0 += pv * vs[kj][od];
            a1 += pv * vs[kj][od + 1];
        }
        oacc0 = oacc0 * f + a0;
        oacc1 = oacc1 * f + a1;
        __syncthreads();
    }

    if (t < QB) lq[t] = l_run;
    __syncthreads();
    int gq = q0 + oqi;
    if (gq < NQ) {
        float inv = 1.f / lq[oqi];
        float* outp = &CTX[(b * NQ + gq) * DIMM + h * HD + od];
        outp[0] = oacc0 * inv;
        outp[1] = oacc1 * inv;
    }
}

// ---------------------------------------------------------------------------
extern "C" void kernel_launch(void* const* d_in, const int* in_sizes, int n_in,
                              void* d_out, int out_size, void* d_ws, size_t ws_size,
                              hipStream_t stream)
{
    const float* hs   = (const float*)d_in[0];   // (B,Q,256)
    const float* rp   = (const float*)d_in[1];   // (B,Q,1,4)
    const float* kv   = (const float*)d_in[2];   // (B,KV,256)
    // d_in[3]: spatial_shapes (int64) -> fixed 64x64
    const int*   msk  = (const int*)d_in[4];     // (B,KV)
    const float* m1w1 = (const float*)d_in[5];
    const float* m1b1 = (const float*)d_in[6];
    const float* m1w2 = (const float*)d_in[7];
    const float* m2w1 = (const float*)d_in[8];
    const float* m2b1 = (const float*)d_in[9];
    const float* m2w2 = (const float*)d_in[10];
    const float* q_w  = (const float*)d_in[11];
    const float* q_b  = (const float*)d_in[12];
    const float* k_w  = (const float*)d_in[13];
    const float* k_b  = (const float*)d_in[14];
    const float* v_w  = (const float*)d_in[15];
    const float* v_b  = (const float*)d_in[16];
    const float* o_w  = (const float*)d_in[17];
    const float* o_b  = (const float*)d_in[18];
    float* out = (float*)d_out;

    float* ws  = (float*)d_ws;
    float* Qp  = ws;                                  // 1800*256
    float* Kp  = Qp + NB * NQ * DIMM;                 // 8192*256
    float* Vp  = Kp + NB * NKV * DIMM;
    float* RX  = Vp + NB * NKV * DIMM;                // 1800*8*64
    float* RY  = RX + NB * NQ * NHEAD * GRID;
    float* CTX = RY + NB * NQ * NHEAD * GRID;         // 1800*256

    const float scale = 0.17677669529663687f;         // 32^-0.5

    // Projections
    gemm_bias_kernel<<<dim3(DIMM / 32, (NB * NQ + 31) / 32), 256, 0, stream>>>(
        hs, q_w, q_b, Qp, NB * NQ, DIMM, DIMM, scale);
    gemm_bias_kernel<<<dim3(DIMM / 32, (NB * NKV) / 32), 256, 0, stream>>>(
        kv, k_w, k_b, Kp, NB * NKV, DIMM, DIMM, 1.f);
    gemm_bias_kernel<<<dim3(DIMM / 32, (NB * NKV) / 32), 256, 0, stream>>>(
        kv, v_w, v_b, Vp, NB * NKV, DIMM, DIMM, 1.f);

    // RPE MLPs
    rpe_kernel<<<NB * NQ, 256, 0, stream>>>(rp, m1w1, m1b1, m1w2,
                                            m2w1, m2b1, m2w2, RX, RY);

    // Attention
    attn_kernel<<<dim3((NQ + QB - 1) / QB, NHEAD, NB), 256, 0, stream>>>(
        Qp, Kp, Vp, RX, RY, msk, CTX);

    // Output projection
    gemm_bias_kernel<<<dim3(DIMM / 32, (NB * NQ + 31) / 32), 256, 0, stream>>>(
        CTX, o_w, o_b, out, NB * NQ, DIMM, DIMM, 1.f);
}

// Round 2
// 297.872 us; speedup vs baseline: 3.5010x; 3.5010x over previous
//
#include <hip/hip_runtime.h>
#include <math.h>

#define NB    2
#define NQ    900
#define NKV   4096
#define DIMM  256
#define NHEAD 8
#define HD    32
#define RPEH  512
#define GRID  64

typedef short short8 __attribute__((ext_vector_type(8)));
typedef float f32x4 __attribute__((ext_vector_type(4)));
typedef unsigned uint2v __attribute__((ext_vector_type(2)));
typedef unsigned short u16;

__device__ inline u16 f2bf(float f) {
    unsigned u = __builtin_bit_cast(unsigned, f);
    u += 0x7fff + ((u >> 16) & 1);
    return (u16)(u >> 16);
}
__device__ inline unsigned packbf2(float a, float b) {
    unsigned ua = __builtin_bit_cast(unsigned, a);
    ua += 0x7fff + ((ua >> 16) & 1);
    unsigned ub = __builtin_bit_cast(unsigned, b);
    ub += 0x7fff + ((ub >> 16) & 1);
    return (ua >> 16) | (ub & 0xffff0000u);
}

// ---------------------------------------------------------------------------
// GEMM: C = (A @ W^T + bias) * scale.  A:(M,K) W:(N,K) row-major fp32.
// OMODE 0: fp32 row-major out. 1: bf16 row-major out. 2: bf16 V-transposed
// out: Vt[((b*8+h)*32+d)*4096 + kv]  (M rows = b*4096+kv, N cols = h*32+d).
// ---------------------------------------------------------------------------
template <int OMODE>
__global__ __launch_bounds__(256) void gemm_bias(
    const float* __restrict__ A, const float* __restrict__ W,
    const float* __restrict__ bias, void* __restrict__ Cout,
    int M, int N, int K, float scale)
{
    __shared__ float As[32][33];
    __shared__ float Ws[32][33];
    const int t  = threadIdx.x;
    const int tr = t >> 4;
    const int tc = t & 15;
    const int brow = blockIdx.y * 32;
    const int bcol = blockIdx.x * 32;
    float acc00 = 0.f, acc01 = 0.f, acc10 = 0.f, acc11 = 0.f;

    for (int kt = 0; kt < K; kt += 32) {
        #pragma unroll
        for (int i = 0; i < 4; ++i) {
            int idx = t + i * 256;
            int r = idx >> 5, c = idx & 31;
            int gr = brow + r;
            As[r][c] = (gr < M) ? A[(size_t)gr * K + kt + c] : 0.f;
            Ws[r][c] = W[(size_t)(bcol + r) * K + kt + c];
        }
        __syncthreads();
        #pragma unroll 8
        for (int k = 0; k < 32; ++k) {
            float a0 = As[tr * 2][k], a1 = As[tr * 2 + 1][k];
            float w0 = Ws[tc * 2][k], w1 = Ws[tc * 2 + 1][k];
            acc00 += a0 * w0; acc01 += a0 * w1;
            acc10 += a1 * w0; acc11 += a1 * w1;
        }
        __syncthreads();
    }
    int gc0 = bcol + tc * 2, gc1 = gc0 + 1;
    int gr0 = brow + tr * 2, gr1 = gr0 + 1;
    float v00 = (acc00 + bias[gc0]) * scale;
    float v01 = (acc01 + bias[gc1]) * scale;
    float v10 = (acc10 + bias[gc0]) * scale;
    float v11 = (acc11 + bias[gc1]) * scale;
    if (OMODE == 0) {
        float* C = (float*)Cout;
        if (gr0 < M) { C[(size_t)gr0 * N + gc0] = v00; C[(size_t)gr0 * N + gc1] = v01; }
        if (gr1 < M) { C[(size_t)gr1 * N + gc0] = v10; C[(size_t)gr1 * N + gc1] = v11; }
    } else if (OMODE == 1) {
        u16* C = (u16*)Cout;
        if (gr0 < M) { C[(size_t)gr0 * N + gc0] = f2bf(v00); C[(size_t)gr0 * N + gc1] = f2bf(v01); }
        if (gr1 < M) { C[(size_t)gr1 * N + gc0] = f2bf(v10); C[(size_t)gr1 * N + gc1] = f2bf(v11); }
    } else {
        u16* C = (u16*)Cout;
        #pragma unroll
        for (int i = 0; i < 2; ++i) {
            int gr = (i == 0) ? gr0 : gr1;
            float va = (i == 0) ? v00 : v10;
            float vb = (i == 0) ? v01 : v11;
            size_t r0 = (size_t)(((gr >> 12) * NHEAD + (gc0 >> 5)) * HD + (gc0 & 31));
            size_t r1 = (size_t)(((gr >> 12) * NHEAD + (gc1 >> 5)) * HD + (gc1 & 31));
            C[r0 * NKV + (gr & 4095)] = f2bf(va);
            C[r1 * NKV + (gr & 4095)] = f2bf(vb);
        }
    }
}

// ---------------------------------------------------------------------------
// RPE MLPs: one block per (b,q). Output stored as [bq][h][64].
// ---------------------------------------------------------------------------
__global__ __launch_bounds__(256) void rpe_kernel(
    const float* __restrict__ ref_pts,
    const float* __restrict__ w1x, const float* __restrict__ b1x,
    const float* __restrict__ w2x,
    const float* __restrict__ w1y, const float* __restrict__ b1y,
    const float* __restrict__ w2y,
    float* __restrict__ rpex, float* __restrict__ rpey)
{
    __shared__ float sw1[2][RPEH][2];
    __shared__ float sb1[2][RPEH];
    __shared__ float sw2[2][NHEAD][RPEH];
    const int t = threadIdx.x;
    for (int i = t; i < RPEH * 2; i += 256) {
        sw1[0][i >> 1][i & 1] = w1x[i];
        sw1[1][i >> 1][i & 1] = w1y[i];
    }
    for (int i = t; i < RPEH; i += 256) { sb1[0][i] = b1x[i]; sb1[1][i] = b1y[i]; }
    for (int i = t; i < NHEAD * RPEH; i += 256) {
        sw2[0][i >> 9][i & 511] = w2x[i];
        sw2[1][i >> 9][i & 511] = w2y[i];
    }
    const int bq = blockIdx.x;
    const float cx = ref_pts[bq * 4 + 0];
    const float cy = ref_pts[bq * 4 + 1];
    const float sw = ref_pts[bq * 4 + 2];
    const float sh = ref_pts[bq * 4 + 3];
    const float xl = (cx - sw * 0.5f) * 1024.f;
    const float xh = (cx + sw * 0.5f) * 1024.f;
    const float yl = (cy - sh * 0.5f) * 1024.f;
    const float yh = (cy + sh * 0.5f) * 1024.f;
    __syncthreads();

    const int pos  = t >> 1;
    const int half = t & 1;
    const int m    = pos >> 6;
    const int i    = pos & 63;
    const float p  = (i + 0.5f) * 16.f;
    const float d0 = (m == 0 ? xl : yl) - p;
    const float d1 = (m == 0 ? xh : yh) - p;

    float acc[NHEAD] = {};
    const int r0 = half * 256;
    for (int r = r0; r < r0 + 256; ++r) {
        float hdn = fmaxf(sw1[m][r][0] * d0 + sw1[m][r][1] * d1 + sb1[m][r], 0.f);
        #pragma unroll
        for (int h = 0; h < NHEAD; ++h) acc[h] += sw2[m][h][r] * hdn;
    }
    #pragma unroll
    for (int h = 0; h < NHEAD; ++h) acc[h] += __shfl_xor(acc[h], 1);
    if (half == 0) {
        float* outp = (m == 0 ? rpex : rpey) + (size_t)bq * (NHEAD * GRID) + i;
        #pragma unroll
        for (int h = 0; h < NHEAD; ++h) outp[h * GRID] = acc[h];
    }
}

// ---------------------------------------------------------------------------
// MFMA attention. Block = (q-tile 64, head, batch) = 4 waves x 16 queries.
// S^T = mfma(Kfrag, Qfrag); wave-parallel online softmax; P^T repacked to
// B-frag order via wave-private LDS; ctx^T = mfma(Vtfrag, Pfrag).
// ---------------------------------------------------------------------------
__global__ __launch_bounds__(256) void attn_mfma(
    const u16* __restrict__ Qbf, const u16* __restrict__ Kbf,
    const u16* __restrict__ Vt,
    const float* __restrict__ RX, const float* __restrict__ RY,
    const int* __restrict__ mask, float* __restrict__ CTX)
{
    __shared__ short8 kbuf[2][4][64];          // [buf][k-subtile][lane] frag order
    __shared__ short8 vbuf[2][4][64];          // [buf][sk*2+dt][lane] frag order
    __shared__ unsigned pbuf[4][2][64][4];     // [wave][k-chunk][lane][dword]
    __shared__ float rx_t[64][68];             // [x][block-q]
    __shared__ float ry_t[64][68];             // [y][block-q]
    __shared__ float mbuf[2][64];

    const int tid  = threadIdx.x;
    const int lane = tid & 63;
    const int w    = tid >> 6;
    const int q15  = lane & 15;
    const int g    = lane >> 4;
    const int qt = blockIdx.x, h = blockIdx.y, b = blockIdx.z;
    const int q0 = qt * 64;

    // stage rpe slices (transposed: [x][q])
    for (int idx = tid; idx < 64 * 64; idx += 256) {
        int x = idx & 63, q = idx >> 6;
        int gq = q0 + q;
        float vx = 0.f, vy = 0.f;
        if (gq < NQ) {
            size_t base = ((size_t)(b * NQ + gq)) * (NHEAD * GRID) + h * GRID + x;
            vx = RX[base]; vy = RY[base];
        }
        rx_t[x][q] = vx; ry_t[x][q] = vy;
    }

    // Q fragment (B-operand: lane holds q-col = lane&15, d = 8*(lane>>4)+j)
    const int wq = w * 16 + q15;
    short8 qf = *(const short8*)(Qbf + ((size_t)(b * NQ + q0 + wq)) * DIMM + h * HD + 8 * g);

    // staging maps
    const int sr = tid >> 2, sc = tid & 3;     // K: row, 16B chunk
    const int vd = tid >> 3, vc = tid & 7;     // V: d-row, 16B chunk
    const size_t kbase = ((size_t)(b * NKV + sr)) * DIMM + h * HD + 8 * sc;
    const size_t vbase = ((size_t)((b * NHEAD + h) * HD + vd)) * NKV + 8 * vc;

    // stage tile 0
    kbuf[0][sr >> 4][(sr & 15) + 16 * sc] = *(const short8*)(Kbf + kbase);
    vbuf[0][(vc >> 2) * 2 + (vd >> 4)][16 * (vc & 3) + (vd & 15)] = *(const short8*)(Vt + vbase);
    if (tid < 64) mbuf[0][tid] = -100.f * (float)mask[b * NKV + tid];
    __syncthreads();

    f32x4 cacc0 = {0.f, 0.f, 0.f, 0.f};
    f32x4 cacc1 = {0.f, 0.f, 0.f, 0.f};
    float m_run = -1e30f, l_run = 0.f;
    int cur = 0;

    for (int t = 0; t < 64; ++t) {
        // ---- stage loads for t+1 (regs) ----
        short8 rk = {}, rv = {};
        float rm = 0.f;
        if (t < 63) {
            size_t kv0n = (size_t)(t + 1) * 64;
            rk = *(const short8*)(Kbf + kbase + kv0n * DIMM);
            rv = *(const short8*)(Vt + vbase + kv0n);
            if (tid < 64) rm = -100.f * (float)mask[b * NKV + kv0n + tid];
        }

        // ---- QK^T: S^T tiles (k rows in m, q in n) ----
        f32x4 zero = {0.f, 0.f, 0.f, 0.f};
        f32x4 s[4];
        #pragma unroll
        for (int kt = 0; kt < 4; ++kt)
            s[kt] = __builtin_amdgcn_mfma_f32_16x16x32_bf16(kbuf[cur][kt][lane], qf, zero, 0, 0, 0);

        // ---- rpe + mask bias ----
        float ryb = ry_t[t][wq];   // y0 == t (KV tile == grid row)
        #pragma unroll
        for (int kt = 0; kt < 4; ++kt) {
            int kb = 16 * kt + 4 * g;
            #pragma unroll
            for (int r = 0; r < 4; ++r)
                s[kt][r] += rx_t[kb + r][wq] + ryb + mbuf[cur][kb + r];
        }

        // ---- online softmax (per q-col; lanes with same lane&15 share q) ----
        float mloc = s[0][0];
        #pragma unroll
        for (int kt = 0; kt < 4; ++kt)
            #pragma unroll
            for (int r = 0; r < 4; ++r) mloc = fmaxf(mloc, s[kt][r]);
        mloc = fmaxf(mloc, __shfl_xor(mloc, 16));
        mloc = fmaxf(mloc, __shfl_xor(mloc, 32));
        float mnew = fmaxf(m_run, mloc);
        float fsc  = __expf(m_run - mnew);
        float psum = 0.f;
        #pragma unroll
        for (int kt = 0; kt < 4; ++kt)
            #pragma unroll
            for (int r = 0; r < 4; ++r) {
                float pv = __expf(s[kt][r] - mnew);
                s[kt][r] = pv;
                psum += pv;
            }
        psum += __shfl_xor(psum, 16);
        psum += __shfl_xor(psum, 32);
        l_run = l_run * fsc + psum;
        m_run = mnew;
        cacc0 *= fsc;
        cacc1 *= fsc;

        // ---- pack P^T into B-frag order (wave-private) ----
        #pragma unroll
        for (int kt = 0; kt < 4; ++kt) {
            unsigned d0 = packbf2(s[kt][0], s[kt][1]);
            unsigned d1 = packbf2(s[kt][2], s[kt][3]);
            int lt = 16 * ((2 * kt + (g >> 1)) & 3) + q15;
            uint2v* dst = (uint2v*)&pbuf[w][kt >> 1][lt][2 * (g & 1)];
            *dst = (uint2v){d0, d1};
        }

        // ---- PV: ctx^T += V^T x P^T ----
        #pragma unroll
        for (int sk = 0; sk < 2; ++sk) {
            short8 pf = *(const short8*)&pbuf[w][sk][lane][0];
            cacc0 = __builtin_amdgcn_mfma_f32_16x16x32_bf16(vbuf[cur][sk * 2 + 0][lane], pf, cacc0, 0, 0, 0);
            cacc1 = __builtin_amdgcn_mfma_f32_16x16x32_bf16(vbuf[cur][sk * 2 + 1][lane], pf, cacc1, 0, 0, 0);
        }

        // ---- write staged tile, one barrier ----
        if (t < 63) {
            kbuf[cur ^ 1][sr >> 4][(sr & 15) + 16 * sc] = rk;
            vbuf[cur ^ 1][(vc >> 2) * 2 + (vd >> 4)][16 * (vc & 3) + (vd & 15)] = rv;
            if (tid < 64) mbuf[cur ^ 1][tid] = rm;
        }
        __syncthreads();
        cur ^= 1;
    }

    // ---- epilogue: ctx^T acc -> CTX (q rows, d cols) ----
    int gq = q0 + wq;
    if (gq < NQ) {
        float inv = 1.f / l_run;
        size_t base = ((size_t)(b * NQ + gq)) * DIMM + h * HD;
        #pragma unroll
        for (int r = 0; r < 4; ++r) {
            CTX[base + 0  + 4 * g + r] = cacc0[r] * inv;
            CTX[base + 16 + 4 * g + r] = cacc1[r] * inv;
        }
    }
}

// ---------------------------------------------------------------------------
extern "C" void kernel_launch(void* const* d_in, const int* in_sizes, int n_in,
                              void* d_out, int out_size, void* d_ws, size_t ws_size,
                              hipStream_t stream)
{
    const float* hs   = (const float*)d_in[0];
    const float* rp   = (const float*)d_in[1];
    const float* kv   = (const float*)d_in[2];
    const int*   msk  = (const int*)d_in[4];
    const float* m1w1 = (const float*)d_in[5];
    const float* m1b1 = (const float*)d_in[6];
    const float* m1w2 = (const float*)d_in[7];
    const float* m2w1 = (const float*)d_in[8];
    const float* m2b1 = (const float*)d_in[9];
    const float* m2w2 = (const float*)d_in[10];
    const float* q_w  = (const float*)d_in[11];
    const float* q_b  = (const float*)d_in[12];
    const float* k_w  = (const float*)d_in[13];
    const float* k_b  = (const float*)d_in[14];
    const float* v_w  = (const float*)d_in[15];
    const float* v_b  = (const float*)d_in[16];
    const float* o_w  = (const float*)d_in[17];
    const float* o_b  = (const float*)d_in[18];
    float* out = (float*)d_out;

    char* p = (char*)d_ws;
    float* RX  = (float*)p; p += (size_t)NB * NQ * NHEAD * GRID * 4;
    float* RY  = (float*)p; p += (size_t)NB * NQ * NHEAD * GRID * 4;
    float* CTX = (float*)p; p += (size_t)NB * NQ * DIMM * 4;
    u16*   Qbf = (u16*)p;   p += (size_t)1920 * DIMM * 2;   // padded rows for q-tile tail
    u16*   Kbf = (u16*)p;   p += (size_t)NB * NKV * DIMM * 2;
    u16*   Vt  = (u16*)p;   p += (size_t)NB * NHEAD * HD * NKV * 2;

    const float scale = 0.17677669529663687f;  // 32^-0.5

    // Projections (bf16 outputs; V transposed per head)
    gemm_bias<1><<<dim3(DIMM / 32, (NB * NQ + 31) / 32), 256, 0, stream>>>(
        hs, q_w, q_b, Qbf, NB * NQ, DIMM, DIMM, scale);
    gemm_bias<1><<<dim3(DIMM / 32, (NB * NKV) / 32), 256, 0, stream>>>(
        kv, k_w, k_b, Kbf, NB * NKV, DIMM, DIMM, 1.f);
    gemm_bias<2><<<dim3(DIMM / 32, (NB * NKV) / 32), 256, 0, stream>>>(
        kv, v_w, v_b, Vt, NB * NKV, DIMM, DIMM, 1.f);

    // RPE MLPs
    rpe_kernel<<<NB * NQ, 256, 0, stream>>>(rp, m1w1, m1b1, m1w2,
                                            m2w1, m2b1, m2w2, RX, RY);

    // MFMA attention
    attn_mfma<<<dim3((NQ + 63) / 64, NHEAD, NB), 256, 0, stream>>>(
        Qbf, Kbf, Vt, RX, RY, msk, CTX);

    // Output projection (fp32)
    gemm_bias<0><<<dim3(DIMM / 32, (NB * NQ + 31) / 32), 256, 0, stream>>>(
        CTX, o_w, o_b, out, NB * NQ, DIMM, DIMM, 1.f);
}

// Round 3
// 194.663 us; speedup vs baseline: 5.3572x; 1.5302x over previous
//
#include <hip/hip_runtime.h>
#include <math.h>

#define NB    2
#define NQ    900
#define NKV   4096
#define DIMM  256
#define NHEAD 8
#define HD    32
#define RPEH  512
#define GRID  64

typedef short short8 __attribute__((ext_vector_type(8)));
typedef float f32x4 __attribute__((ext_vector_type(4)));
typedef unsigned uint2v __attribute__((ext_vector_type(2)));
typedef unsigned short u16;
typedef unsigned short u16x4 __attribute__((ext_vector_type(4)));

__device__ inline u16 f2bf(float f) {
    unsigned u = __builtin_bit_cast(unsigned, f);
    u += 0x7fff + ((u >> 16) & 1);
    return (u16)(u >> 16);
}
__device__ inline unsigned packbf2(float a, float b) {
    unsigned ua = __builtin_bit_cast(unsigned, a);
    ua += 0x7fff + ((ua >> 16) & 1);
    unsigned ub = __builtin_bit_cast(unsigned, b);
    ub += 0x7fff + ((ub >> 16) & 1);
    return (ua >> 16) | (ub & 0xffff0000u);
}

// ---------------------------------------------------------------------------
// fp32 -> bf16 conversion prepass (hs, kv, q_w, k_w, v_w), one launch.
// ---------------------------------------------------------------------------
#define HS4  115200   // 1800*256/4
#define KV4  524288   // 8192*256/4
#define W4   16384    // 256*256/4
__global__ __launch_bounds__(256) void conv_bf16(
    const float* __restrict__ hs, const float* __restrict__ kv,
    const float* __restrict__ qw, const float* __restrict__ kw,
    const float* __restrict__ vw,
    u16* __restrict__ hsbf, u16* __restrict__ kvbf,
    u16* __restrict__ qwbf, u16* __restrict__ kwbf, u16* __restrict__ vwbf)
{
    const int total = HS4 + KV4 + 3 * W4;
    for (int g = blockIdx.x * 256 + threadIdx.x; g < total; g += gridDim.x * 256) {
        const float* s; u16* d; int off;
        if (g < HS4)                       { s = hs; d = hsbf; off = g; }
        else if (g < HS4 + KV4)            { s = kv; d = kvbf; off = g - HS4; }
        else if (g < HS4 + KV4 + W4)       { s = qw; d = qwbf; off = g - HS4 - KV4; }
        else if (g < HS4 + KV4 + 2 * W4)   { s = kw; d = kwbf; off = g - HS4 - KV4 - W4; }
        else                               { s = vw; d = vwbf; off = g - HS4 - KV4 - 2 * W4; }
        f32x4 v = *(const f32x4*)(s + (size_t)off * 4);
        *(u16x4*)(d + (size_t)off * 4) =
            (u16x4){f2bf(v[0]), f2bf(v[1]), f2bf(v[2]), f2bf(v[3])};
    }
}

// ---------------------------------------------------------------------------
// bf16 MFMA projection GEMM: out = (A @ W^T + bias) * scale.
// A:(M,256) bf16 row-major, W:(256,256) bf16 row-major. Tile 128x128, BK=32,
// 4 waves (2x2), double-buffered LDS, XOR-swizzled 16B slots.
// blockIdx.z==0 -> W0/B0 -> outRow (bf16 row-major);
// blockIdx.z==1 -> W1/B1 -> outVt  (bf16, Vt[((b*8+h)*32+d)*4096 + kv]).
// ---------------------------------------------------------------------------
__global__ __launch_bounds__(256) void proj_mfma(
    const u16* __restrict__ A,
    const u16* __restrict__ W0, const float* __restrict__ B0,
    const u16* __restrict__ W1, const float* __restrict__ B1,
    u16* __restrict__ outRow, u16* __restrict__ outVt,
    int M, float scale)
{
    __shared__ u16 Abuf[2][4096];   // 512 slots x 8 bf16
    __shared__ u16 Bbuf[2][4096];

    const u16* W = W0; const float* bias = B0; bool vt = false;
    if (blockIdx.z == 1) { W = W1; bias = B1; vt = true; }

    const int t    = threadIdx.x;
    const int lane = t & 63;
    const int w    = t >> 6;
    const int wm   = w >> 1, wn = w & 1;
    const int m0   = blockIdx.x * 128;
    const int n0   = blockIdx.y * 128;

    // staging: thread moves slots t and t+256 of each matrix per K-step
    const int r0 = t >> 2, c0 = t & 3;
    const int r1 = r0 + 64;
    const int s0 = r0 * 4 + (c0 ^ (r0 & 3));
    const int s1 = r1 * 4 + (c0 ^ (r1 & 3));
    const u16* Arow0 = A + (size_t)(m0 + r0) * DIMM + c0 * 8;
    const u16* Arow1 = A + (size_t)(m0 + r1) * DIMM + c0 * 8;
    const u16* Wrow0 = W + (size_t)(n0 + r0) * DIMM + c0 * 8;
    const u16* Wrow1 = W + (size_t)(n0 + r1) * DIMM + c0 * 8;

    // fragment slots
    const int fr = lane & 15, fkc = lane >> 4;
    int aslot[4], bslot[4];
    #pragma unroll
    for (int f = 0; f < 4; ++f) {
        int ar = wm * 64 + f * 16 + fr;
        int br = wn * 64 + f * 16 + fr;
        aslot[f] = ar * 4 + (fkc ^ (ar & 3));
        bslot[f] = br * 4 + (fkc ^ (br & 3));
    }
    float bv[4];
    #pragma unroll
    for (int f = 0; f < 4; ++f) bv[f] = bias[n0 + wn * 64 + f * 16 + fr];

    f32x4 acc[4][4] = {};

    // prologue: stage K-step 0
    {
        short8 a0 = *(const short8*)(Arow0);
        short8 a1 = *(const short8*)(Arow1);
        short8 b0 = *(const short8*)(Wrow0);
        short8 b1 = *(const short8*)(Wrow1);
        *(short8*)&Abuf[0][s0 * 8] = a0;
        *(short8*)&Abuf[0][s1 * 8] = a1;
        *(short8*)&Bbuf[0][s0 * 8] = b0;
        *(short8*)&Bbuf[0][s1 * 8] = b1;
    }
    __syncthreads();

    int cur = 0;
    for (int kt = 0; kt < 8; ++kt) {
        short8 na0, na1, nb0, nb1;
        if (kt < 7) {
            int ko = (kt + 1) * 32;
            na0 = *(const short8*)(Arow0 + ko);
            na1 = *(const short8*)(Arow1 + ko);
            nb0 = *(const short8*)(Wrow0 + ko);
            nb1 = *(const short8*)(Wrow1 + ko);
        }
        short8 af[4], bf[4];
        #pragma unroll
        for (int f = 0; f < 4; ++f) {
            af[f] = *(const short8*)&Abuf[cur][aslot[f] * 8];
            bf[f] = *(const short8*)&Bbuf[cur][bslot[f] * 8];
        }
        #pragma unroll
        for (int i = 0; i < 4; ++i)
            #pragma unroll
            for (int j = 0; j < 4; ++j)
                acc[i][j] = __builtin_amdgcn_mfma_f32_16x16x32_bf16(af[i], bf[j], acc[i][j], 0, 0, 0);
        if (kt < 7) {
            *(short8*)&Abuf[cur ^ 1][s0 * 8] = na0;
            *(short8*)&Abuf[cur ^ 1][s1 * 8] = na1;
            *(short8*)&Bbuf[cur ^ 1][s0 * 8] = nb0;
            *(short8*)&Bbuf[cur ^ 1][s1 * 8] = nb1;
        }
        __syncthreads();
        cur ^= 1;
    }

    // epilogue
    #pragma unroll
    for (int i = 0; i < 4; ++i) {
        int mbase = m0 + wm * 64 + i * 16 + 4 * fkc;
        #pragma unroll
        for (int j = 0; j < 4; ++j) {
            int n = n0 + wn * 64 + j * 16 + fr;
            #pragma unroll
            for (int r = 0; r < 4; ++r) {
                int gm = mbase + r;
                if (gm < M) {
                    float v = (acc[i][j][r] + bv[j]) * scale;
                    if (!vt) {
                        outRow[(size_t)gm * DIMM + n] = f2bf(v);
                    } else {
                        int bb = gm >> 12, kvi = gm & 4095;
                        int hh = n >> 5, dd = n & 31;
                        outVt[(size_t)((bb * NHEAD + hh) * HD + dd) * NKV + kvi] = f2bf(v);
                    }
                }
            }
        }
    }
}

// ---------------------------------------------------------------------------
// RPE MLPs, restructured: lane = grid position p (64 lanes = 64 positions).
// hidden = relu(alpha - beta*p); alpha,beta wave-uniform per (bq,r) ->
// all weight LDS reads are broadcasts (conflict-free). Each wave: one
// (m, group of 4 bq) task over all 512 hidden units. 225 blocks x 4 waves.
// ---------------------------------------------------------------------------
__global__ __launch_bounds__(256) void rpe_kernel(
    const float* __restrict__ ref_pts,
    const float* __restrict__ w1x, const float* __restrict__ b1x,
    const float* __restrict__ w2x,
    const float* __restrict__ w1y, const float* __restrict__ b1y,
    const float* __restrict__ w2y,
    float* __restrict__ rpex, float* __restrict__ rpey)
{
    __shared__ f32x4 wpk[2][RPEH];            // {a, b, bias, a+b}
    __shared__ float w2t[2][RPEH][NHEAD];     // transposed second layer

    const int t = threadIdx.x;
    for (int i = t; i < 2 * RPEH; i += 256) {
        int m = i >> 9, r = i & 511;
        const float* w1 = m ? w1y : w1x;
        const float* b1 = m ? b1y : b1x;
        float a = w1[r * 2], b = w1[r * 2 + 1];
        wpk[m][r] = (f32x4){a, b, b1[r], a + b};
    }
    for (int i = t; i < 2 * RPEH * NHEAD; i += 256) {
        int m = i >> 12, j = i & 4095;
        int h = j >> 9, r = j & 511;
        const float* w2 = m ? w2y : w2x;
        w2t[m][r][h] = w2[h * RPEH + r];
    }
    __syncthreads();

    const int lane = t & 63;
    const int w    = t >> 6;
    const int task = blockIdx.x * 4 + w;      // 0..899
    const int m    = task >= 450 ? 1 : 0;
    const int grp  = m ? task - 450 : task;
    const int bq0  = grp * 4;
    const float p  = (lane + 0.5f) * 16.f;

    float lo[4], hi[4];
    #pragma unroll
    for (int j = 0; j < 4; ++j) {
        const float* q = ref_pts + (size_t)(bq0 + j) * 4;
        float c = m ? q[1] : q[0];
        float s = m ? q[3] : q[2];
        lo[j] = (c - s * 0.5f) * 1024.f;
        hi[j] = (c + s * 0.5f) * 1024.f;
    }

    float acc[4][8] = {};
    #pragma unroll 2
    for (int r = 0; r < RPEH; ++r) {
        f32x4 W  = wpk[m][r];
        f32x4 u0 = *(const f32x4*)&w2t[m][r][0];
        f32x4 u1 = *(const f32x4*)&w2t[m][r][4];
        float bp = W[3] * p;
        #pragma unroll
        for (int j = 0; j < 4; ++j) {
            float al  = W[0] * lo[j] + W[1] * hi[j] + W[2];
            float hid = fmaxf(al - bp, 0.f);
            acc[j][0] += u0[0] * hid;
            acc[j][1] += u0[1] * hid;
            acc[j][2] += u0[2] * hid;
            acc[j][3] += u0[3] * hid;
            acc[j][4] += u1[0] * hid;
            acc[j][5] += u1[1] * hid;
            acc[j][6] += u1[2] * hid;
            acc[j][7] += u1[3] * hid;
        }
    }

    float* outp = m ? rpey : rpex;
    #pragma unroll
    for (int j = 0; j < 4; ++j) {
        size_t base = (size_t)(bq0 + j) * (NHEAD * GRID) + lane;
        #pragma unroll
        for (int h = 0; h < 8; ++h) outp[base + h * GRID] = acc[j][h];
    }
}

// ---------------------------------------------------------------------------
// MFMA attention (unchanged from round 2 — verified passing).
// ---------------------------------------------------------------------------
__global__ __launch_bounds__(256) void attn_mfma(
    const u16* __restrict__ Qbf, const u16* __restrict__ Kbf,
    const u16* __restrict__ Vt,
    const float* __restrict__ RX, const float* __restrict__ RY,
    const int* __restrict__ mask, float* __restrict__ CTX)
{
    __shared__ short8 kbuf[2][4][64];
    __shared__ short8 vbuf[2][4][64];
    __shared__ unsigned pbuf[4][2][64][4];
    __shared__ float rx_t[64][68];
    __shared__ float ry_t[64][68];
    __shared__ float mbuf[2][64];

    const int tid  = threadIdx.x;
    const int lane = tid & 63;
    const int w    = tid >> 6;
    const int q15  = lane & 15;
    const int g    = lane >> 4;
    const int qt = blockIdx.x, h = blockIdx.y, b = blockIdx.z;
    const int q0 = qt * 64;

    for (int idx = tid; idx < 64 * 64; idx += 256) {
        int x = idx & 63, q = idx >> 6;
        int gq = q0 + q;
        float vx = 0.f, vy = 0.f;
        if (gq < NQ) {
            size_t base = ((size_t)(b * NQ + gq)) * (NHEAD * GRID) + h * GRID + x;
            vx = RX[base]; vy = RY[base];
        }
        rx_t[x][q] = vx; ry_t[x][q] = vy;
    }

    const int wq = w * 16 + q15;
    short8 qf = *(const short8*)(Qbf + ((size_t)(b * NQ + q0 + wq)) * DIMM + h * HD + 8 * g);

    const int sr = tid >> 2, sc = tid & 3;
    const int vd = tid >> 3, vc = tid & 7;
    const size_t kbase = ((size_t)(b * NKV + sr)) * DIMM + h * HD + 8 * sc;
    const size_t vbase = ((size_t)((b * NHEAD + h) * HD + vd)) * NKV + 8 * vc;

    kbuf[0][sr >> 4][(sr & 15) + 16 * sc] = *(const short8*)(Kbf + kbase);
    vbuf[0][(vc >> 2) * 2 + (vd >> 4)][16 * (vc & 3) + (vd & 15)] = *(const short8*)(Vt + vbase);
    if (tid < 64) mbuf[0][tid] = -100.f * (float)mask[b * NKV + tid];
    __syncthreads();

    f32x4 cacc0 = {0.f, 0.f, 0.f, 0.f};
    f32x4 cacc1 = {0.f, 0.f, 0.f, 0.f};
    float m_run = -1e30f, l_run = 0.f;
    int cur = 0;

    for (int t = 0; t < 64; ++t) {
        short8 rk = {}, rv = {};
        float rm = 0.f;
        if (t < 63) {
            size_t kv0n = (size_t)(t + 1) * 64;
            rk = *(const short8*)(Kbf + kbase + kv0n * DIMM);
            rv = *(const short8*)(Vt + vbase + kv0n);
            if (tid < 64) rm = -100.f * (float)mask[b * NKV + kv0n + tid];
        }

        f32x4 zero = {0.f, 0.f, 0.f, 0.f};
        f32x4 s[4];
        #pragma unroll
        for (int kt = 0; kt < 4; ++kt)
            s[kt] = __builtin_amdgcn_mfma_f32_16x16x32_bf16(kbuf[cur][kt][lane], qf, zero, 0, 0, 0);

        float ryb = ry_t[t][wq];
        #pragma unroll
        for (int kt = 0; kt < 4; ++kt) {
            int kb = 16 * kt + 4 * g;
            #pragma unroll
            for (int r = 0; r < 4; ++r)
                s[kt][r] += rx_t[kb + r][wq] + ryb + mbuf[cur][kb + r];
        }

        float mloc = s[0][0];
        #pragma unroll
        for (int kt = 0; kt < 4; ++kt)
            #pragma unroll
            for (int r = 0; r < 4; ++r) mloc = fmaxf(mloc, s[kt][r]);
        mloc = fmaxf(mloc, __shfl_xor(mloc, 16));
        mloc = fmaxf(mloc, __shfl_xor(mloc, 32));
        float mnew = fmaxf(m_run, mloc);
        float fsc  = __expf(m_run - mnew);
        float psum = 0.f;
        #pragma unroll
        for (int kt = 0; kt < 4; ++kt)
            #pragma unroll
            for (int r = 0; r < 4; ++r) {
                float pv = __expf(s[kt][r] - mnew);
                s[kt][r] = pv;
                psum += pv;
            }
        psum += __shfl_xor(psum, 16);
        psum += __shfl_xor(psum, 32);
        l_run = l_run * fsc + psum;
        m_run = mnew;
        cacc0 *= fsc;
        cacc1 *= fsc;

        #pragma unroll
        for (int kt = 0; kt < 4; ++kt) {
            unsigned d0 = packbf2(s[kt][0], s[kt][1]);
            unsigned d1 = packbf2(s[kt][2], s[kt][3]);
            int lt = 16 * ((2 * kt + (g >> 1)) & 3) + q15;
            uint2v* dst = (uint2v*)&pbuf[w][kt >> 1][lt][2 * (g & 1)];
            *dst = (uint2v){d0, d1};
        }

        #pragma unroll
        for (int sk = 0; sk < 2; ++sk) {
            short8 pf = *(const short8*)&pbuf[w][sk][lane][0];
            cacc0 = __builtin_amdgcn_mfma_f32_16x16x32_bf16(vbuf[cur][sk * 2 + 0][lane], pf, cacc0, 0, 0, 0);
            cacc1 = __builtin_amdgcn_mfma_f32_16x16x32_bf16(vbuf[cur][sk * 2 + 1][lane], pf, cacc1, 0, 0, 0);
        }

        if (t < 63) {
            kbuf[cur ^ 1][sr >> 4][(sr & 15) + 16 * sc] = rk;
            vbuf[cur ^ 1][(vc >> 2) * 2 + (vd >> 4)][16 * (vc & 3) + (vd & 15)] = rv;
            if (tid < 64) mbuf[cur ^ 1][tid] = rm;
        }
        __syncthreads();
        cur ^= 1;
    }

    int gq = q0 + wq;
    if (gq < NQ) {
        float inv = 1.f / l_run;
        size_t base = ((size_t)(b * NQ + gq)) * DIMM + h * HD;
        #pragma unroll
        for (int r = 0; r < 4; ++r) {
            CTX[base + 0  + 4 * g + r] = cacc0[r] * inv;
            CTX[base + 16 + 4 * g + r] = cacc1[r] * inv;
        }
    }
}

// ---------------------------------------------------------------------------
// fp32 GEMM for the output projection (precision-critical final linear).
// ---------------------------------------------------------------------------
__global__ __launch_bounds__(256) void gemm_bias_f32(
    const float* __restrict__ A, const float* __restrict__ W,
    const float* __restrict__ bias, float* __restrict__ C,
    int M, int N, int K)
{
    __shared__ float As[32][33];
    __shared__ float Ws[32][33];
    const int t  = threadIdx.x;
    const int tr = t >> 4;
    const int tc = t & 15;
    const int brow = blockIdx.y * 32;
    const int bcol = blockIdx.x * 32;
    float acc00 = 0.f, acc01 = 0.f, acc10 = 0.f, acc11 = 0.f;

    for (int kt = 0; kt < K; kt += 32) {
        #pragma unroll
        for (int i = 0; i < 4; ++i) {
            int idx = t + i * 256;
            int r = idx >> 5, c = idx & 31;
            int gr = brow + r;
            As[r][c] = (gr < M) ? A[(size_t)gr * K + kt + c] : 0.f;
            Ws[r][c] = W[(size_t)(bcol + r) * K + kt + c];
        }
        __syncthreads();
        #pragma unroll 8
        for (int k = 0; k < 32; ++k) {
            float a0 = As[tr * 2][k], a1 = As[tr * 2 + 1][k];
            float w0 = Ws[tc * 2][k], w1 = Ws[tc * 2 + 1][k];
            acc00 += a0 * w0; acc01 += a0 * w1;
            acc10 += a1 * w0; acc11 += a1 * w1;
        }
        __syncthreads();
    }
    int gc0 = bcol + tc * 2, gc1 = gc0 + 1;
    int gr0 = brow + tr * 2, gr1 = gr0 + 1;
    if (gr0 < M) {
        C[(size_t)gr0 * N + gc0] = acc00 + bias[gc0];
        C[(size_t)gr0 * N + gc1] = acc01 + bias[gc1];
    }
    if (gr1 < M) {
        C[(size_t)gr1 * N + gc0] = acc10 + bias[gc0];
        C[(size_t)gr1 * N + gc1] = acc11 + bias[gc1];
    }
}

// ---------------------------------------------------------------------------
extern "C" void kernel_launch(void* const* d_in, const int* in_sizes, int n_in,
                              void* d_out, int out_size, void* d_ws, size_t ws_size,
                              hipStream_t stream)
{
    const float* hs   = (const float*)d_in[0];
    const float* rp   = (const float*)d_in[1];
    const float* kv   = (const float*)d_in[2];
    const int*   msk  = (const int*)d_in[4];
    const float* m1w1 = (const float*)d_in[5];
    const float* m1b1 = (const float*)d_in[6];
    const float* m1w2 = (const float*)d_in[7];
    const float* m2w1 = (const float*)d_in[8];
    const float* m2b1 = (const float*)d_in[9];
    const float* m2w2 = (const float*)d_in[10];
    const float* q_w  = (const float*)d_in[11];
    const float* q_b  = (const float*)d_in[12];
    const float* k_w  = (const float*)d_in[13];
    const float* k_b  = (const float*)d_in[14];
    const float* v_w  = (const float*)d_in[15];
    const float* v_b  = (const float*)d_in[16];
    const float* o_w  = (const float*)d_in[17];
    const float* o_b  = (const float*)d_in[18];
    float* out = (float*)d_out;

    char* p = (char*)d_ws;
    float* RX   = (float*)p; p += (size_t)NB * NQ * NHEAD * GRID * 4;
    float* RY   = (float*)p; p += (size_t)NB * NQ * NHEAD * GRID * 4;
    float* CTX  = (float*)p; p += (size_t)NB * NQ * DIMM * 4;
    u16*   Qbf  = (u16*)p;   p += (size_t)1920 * DIMM * 2;
    u16*   Kbf  = (u16*)p;   p += (size_t)NB * NKV * DIMM * 2;
    u16*   Vt   = (u16*)p;   p += (size_t)NB * NHEAD * HD * NKV * 2;
    u16*   hsbf = (u16*)p;   p += (size_t)1920 * DIMM * 2;
    u16*   kvbf = (u16*)p;   p += (size_t)NB * NKV * DIMM * 2;
    u16*   qwbf = (u16*)p;   p += (size_t)DIMM * DIMM * 2;
    u16*   kwbf = (u16*)p;   p += (size_t)DIMM * DIMM * 2;
    u16*   vwbf = (u16*)p;   p += (size_t)DIMM * DIMM * 2;

    const float scale = 0.17677669529663687f;  // 32^-0.5

    // 1) fp32 -> bf16 conversion
    conv_bf16<<<1024, 256, 0, stream>>>(hs, kv, q_w, k_w, v_w,
                                        hsbf, kvbf, qwbf, kwbf, vwbf);

    // 2) Q projection (bf16 MFMA, scale folded)
    proj_mfma<<<dim3(15, 2, 1), 256, 0, stream>>>(
        hsbf, qwbf, q_b, nullptr, nullptr, Qbf, nullptr, NB * NQ, scale);

    // 3) K + V projections fused (z=0 -> K row-major, z=1 -> V transposed)
    proj_mfma<<<dim3(64, 2, 2), 256, 0, stream>>>(
        kvbf, kwbf, k_b, vwbf, v_b, Kbf, Vt, NB * NKV, 1.f);

    // 4) RPE MLPs
    rpe_kernel<<<225, 256, 0, stream>>>(rp, m1w1, m1b1, m1w2,
                                        m2w1, m2b1, m2w2, RX, RY);

    // 5) MFMA attention
    attn_mfma<<<dim3((NQ + 63) / 64, NHEAD, NB), 256, 0, stream>>>(
        Qbf, Kbf, Vt, RX, RY, msk, CTX);

    // 6) Output projection (fp32)
    gemm_bias_f32<<<dim3(DIMM / 32, (NB * NQ + 31) / 32), 256, 0, stream>>>(
        CTX, o_w, o_b, out, NB * NQ, DIMM, DIMM);
}

// Round 4
// 159.929 us; speedup vs baseline: 6.5207x; 1.2172x over previous
//
#include <hip/hip_runtime.h>
#include <math.h>

#define NB    2
#define NQ    900
#define NQP   960
#define NKV   4096
#define DIMM  256
#define NHEAD 8
#define HD    32
#define RPEH  512
#define GRID  64
#define SPLIT 4
#define KVSEG 1024
#define NT    16

typedef short short8 __attribute__((ext_vector_type(8)));
typedef float f32x4 __attribute__((ext_vector_type(4)));
typedef unsigned uint2v __attribute__((ext_vector_type(2)));
typedef unsigned short u16;
typedef unsigned short u16x4 __attribute__((ext_vector_type(4)));

__device__ inline u16 f2bf(float f) {
    unsigned u = __builtin_bit_cast(unsigned, f);
    u += 0x7fff + ((u >> 16) & 1);
    return (u16)(u >> 16);
}
__device__ inline unsigned packbf2(float a, float b) {
    unsigned ua = __builtin_bit_cast(unsigned, a);
    ua += 0x7fff + ((ua >> 16) & 1);
    unsigned ub = __builtin_bit_cast(unsigned, b);
    ub += 0x7fff + ((ub >> 16) & 1);
    return (ua >> 16) | (ub & 0xffff0000u);
}

// ---------------------------------------------------------------------------
// fp32 -> bf16 conversion prepass (hs, kv, q_w, k_w, v_w), one launch.
// ---------------------------------------------------------------------------
#define HS4  115200   // 1800*256/4
#define KV4  524288   // 8192*256/4
#define W4   16384    // 256*256/4
__global__ __launch_bounds__(256) void conv_bf16(
    const float* __restrict__ hs, const float* __restrict__ kv,
    const float* __restrict__ qw, const float* __restrict__ kw,
    const float* __restrict__ vw,
    u16* __restrict__ hsbf, u16* __restrict__ kvbf,
    u16* __restrict__ qwbf, u16* __restrict__ kwbf, u16* __restrict__ vwbf)
{
    const int total = HS4 + KV4 + 3 * W4;
    for (int g = blockIdx.x * 256 + threadIdx.x; g < total; g += gridDim.x * 256) {
        const float* s; u16* d; int off;
        if (g < HS4)                       { s = hs; d = hsbf; off = g; }
        else if (g < HS4 + KV4)            { s = kv; d = kvbf; off = g - HS4; }
        else if (g < HS4 + KV4 + W4)       { s = qw; d = qwbf; off = g - HS4 - KV4; }
        else if (g < HS4 + KV4 + 2 * W4)   { s = kw; d = kwbf; off = g - HS4 - KV4 - W4; }
        else                               { s = vw; d = vwbf; off = g - HS4 - KV4 - 2 * W4; }
        f32x4 v = *(const f32x4*)(s + (size_t)off * 4);
        *(u16x4*)(d + (size_t)off * 4) =
            (u16x4){f2bf(v[0]), f2bf(v[1]), f2bf(v[2]), f2bf(v[3])};
    }
}

// ---------------------------------------------------------------------------
// bf16 MFMA projection GEMM (unchanged, verified).
// ---------------------------------------------------------------------------
__global__ __launch_bounds__(256) void proj_mfma(
    const u16* __restrict__ A,
    const u16* __restrict__ W0, const float* __restrict__ B0,
    const u16* __restrict__ W1, const float* __restrict__ B1,
    u16* __restrict__ outRow, u16* __restrict__ outVt,
    int M, float scale)
{
    __shared__ u16 Abuf[2][4096];
    __shared__ u16 Bbuf[2][4096];

    const u16* W = W0; const float* bias = B0; bool vt = false;
    if (blockIdx.z == 1) { W = W1; bias = B1; vt = true; }

    const int t    = threadIdx.x;
    const int lane = t & 63;
    const int w    = t >> 6;
    const int wm   = w >> 1, wn = w & 1;
    const int m0   = blockIdx.x * 128;
    const int n0   = blockIdx.y * 128;

    const int r0 = t >> 2, c0 = t & 3;
    const int r1 = r0 + 64;
    const int s0 = r0 * 4 + (c0 ^ (r0 & 3));
    const int s1 = r1 * 4 + (c0 ^ (r1 & 3));
    const u16* Arow0 = A + (size_t)(m0 + r0) * DIMM + c0 * 8;
    const u16* Arow1 = A + (size_t)(m0 + r1) * DIMM + c0 * 8;
    const u16* Wrow0 = W + (size_t)(n0 + r0) * DIMM + c0 * 8;
    const u16* Wrow1 = W + (size_t)(n0 + r1) * DIMM + c0 * 8;

    const int fr = lane & 15, fkc = lane >> 4;
    int aslot[4], bslot[4];
    #pragma unroll
    for (int f = 0; f < 4; ++f) {
        int ar = wm * 64 + f * 16 + fr;
        int br = wn * 64 + f * 16 + fr;
        aslot[f] = ar * 4 + (fkc ^ (ar & 3));
        bslot[f] = br * 4 + (fkc ^ (br & 3));
    }
    float bv[4];
    #pragma unroll
    for (int f = 0; f < 4; ++f) bv[f] = bias[n0 + wn * 64 + f * 16 + fr];

    f32x4 acc[4][4] = {};

    {
        short8 a0 = *(const short8*)(Arow0);
        short8 a1 = *(const short8*)(Arow1);
        short8 b0 = *(const short8*)(Wrow0);
        short8 b1 = *(const short8*)(Wrow1);
        *(short8*)&Abuf[0][s0 * 8] = a0;
        *(short8*)&Abuf[0][s1 * 8] = a1;
        *(short8*)&Bbuf[0][s0 * 8] = b0;
        *(short8*)&Bbuf[0][s1 * 8] = b1;
    }
    __syncthreads();

    int cur = 0;
    for (int kt = 0; kt < 8; ++kt) {
        short8 na0, na1, nb0, nb1;
        if (kt < 7) {
            int ko = (kt + 1) * 32;
            na0 = *(const short8*)(Arow0 + ko);
            na1 = *(const short8*)(Arow1 + ko);
            nb0 = *(const short8*)(Wrow0 + ko);
            nb1 = *(const short8*)(Wrow1 + ko);
        }
        short8 af[4], bf[4];
        #pragma unroll
        for (int f = 0; f < 4; ++f) {
            af[f] = *(const short8*)&Abuf[cur][aslot[f] * 8];
            bf[f] = *(const short8*)&Bbuf[cur][bslot[f] * 8];
        }
        #pragma unroll
        for (int i = 0; i < 4; ++i)
            #pragma unroll
            for (int j = 0; j < 4; ++j)
                acc[i][j] = __builtin_amdgcn_mfma_f32_16x16x32_bf16(af[i], bf[j], acc[i][j], 0, 0, 0);
        if (kt < 7) {
            *(short8*)&Abuf[cur ^ 1][s0 * 8] = na0;
            *(short8*)&Abuf[cur ^ 1][s1 * 8] = na1;
            *(short8*)&Bbuf[cur ^ 1][s0 * 8] = nb0;
            *(short8*)&Bbuf[cur ^ 1][s1 * 8] = nb1;
        }
        __syncthreads();
        cur ^= 1;
    }

    #pragma unroll
    for (int i = 0; i < 4; ++i) {
        int mbase = m0 + wm * 64 + i * 16 + 4 * fkc;
        #pragma unroll
        for (int j = 0; j < 4; ++j) {
            int n = n0 + wn * 64 + j * 16 + fr;
            #pragma unroll
            for (int r = 0; r < 4; ++r) {
                int gm = mbase + r;
                if (gm < M) {
                    float v = (acc[i][j][r] + bv[j]) * scale;
                    if (!vt) {
                        outRow[(size_t)gm * DIMM + n] = f2bf(v);
                    } else {
                        int bb = gm >> 12, kvi = gm & 4095;
                        int hh = n >> 5, dd = n & 31;
                        outVt[(size_t)((bb * NHEAD + hh) * HD + dd) * NKV + kvi] = f2bf(v);
                    }
                }
            }
        }
    }
}

// ---------------------------------------------------------------------------
// RPE MLPs (unchanged from round 3).
// ---------------------------------------------------------------------------
__global__ __launch_bounds__(256) void rpe_kernel(
    const float* __restrict__ ref_pts,
    const float* __restrict__ w1x, const float* __restrict__ b1x,
    const float* __restrict__ w2x,
    const float* __restrict__ w1y, const float* __restrict__ b1y,
    const float* __restrict__ w2y,
    float* __restrict__ rpex, float* __restrict__ rpey)
{
    __shared__ f32x4 wpk[2][RPEH];
    __shared__ float w2t[2][RPEH][NHEAD];

    const int t = threadIdx.x;
    for (int i = t; i < 2 * RPEH; i += 256) {
        int m = i >> 9, r = i & 511;
        const float* w1 = m ? w1y : w1x;
        const float* b1 = m ? b1y : b1x;
        float a = w1[r * 2], b = w1[r * 2 + 1];
        wpk[m][r] = (f32x4){a, b, b1[r], a + b};
    }
    for (int i = t; i < 2 * RPEH * NHEAD; i += 256) {
        int m = i >> 12, j = i & 4095;
        int h = j >> 9, r = j & 511;
        const float* w2 = m ? w2y : w2x;
        w2t[m][r][h] = w2[h * RPEH + r];
    }
    __syncthreads();

    const int lane = t & 63;
    const int w    = t >> 6;
    const int task = blockIdx.x * 4 + w;
    const int m    = task >= 450 ? 1 : 0;
    const int grp  = m ? task - 450 : task;
    const int bq0  = grp * 4;
    const float p  = (lane + 0.5f) * 16.f;

    float lo[4], hi[4];
    #pragma unroll
    for (int j = 0; j < 4; ++j) {
        const float* q = ref_pts + (size_t)(bq0 + j) * 4;
        float c = m ? q[1] : q[0];
        float s = m ? q[3] : q[2];
        lo[j] = (c - s * 0.5f) * 1024.f;
        hi[j] = (c + s * 0.5f) * 1024.f;
    }

    float acc[4][8] = {};
    #pragma unroll 2
    for (int r = 0; r < RPEH; ++r) {
        f32x4 W  = wpk[m][r];
        f32x4 u0 = *(const f32x4*)&w2t[m][r][0];
        f32x4 u1 = *(const f32x4*)&w2t[m][r][4];
        float bp = W[3] * p;
        #pragma unroll
        for (int j = 0; j < 4; ++j) {
            float al  = W[0] * lo[j] + W[1] * hi[j] + W[2];
            float hid = fmaxf(al - bp, 0.f);
            acc[j][0] += u0[0] * hid;
            acc[j][1] += u0[1] * hid;
            acc[j][2] += u0[2] * hid;
            acc[j][3] += u0[3] * hid;
            acc[j][4] += u1[0] * hid;
            acc[j][5] += u1[1] * hid;
            acc[j][6] += u1[2] * hid;
            acc[j][7] += u1[3] * hid;
        }
    }

    float* outp = m ? rpey : rpex;
    #pragma unroll
    for (int j = 0; j < 4; ++j) {
        size_t base = (size_t)(bq0 + j) * (NHEAD * GRID) + lane;
        #pragma unroll
        for (int h = 0; h < 8; ++h) outp[base + h * GRID] = acc[j][h];
    }
}

// ---------------------------------------------------------------------------
// MFMA attention, KV-split flash-decode. Block = (q-tile 64, head, b*4+split).
// Each block covers KV segment [sp*1024, sp*1024+1024), emits unnormalized
// partial ctx + (m,l). rx bias in registers (per-lane pattern is fixed);
// ry bias in a small [16][68] LDS tile.
// ---------------------------------------------------------------------------
__global__ __launch_bounds__(256) void attn_mfma(
    const u16* __restrict__ Qbf, const u16* __restrict__ Kbf,
    const u16* __restrict__ Vt,
    const float* __restrict__ RX, const float* __restrict__ RY,
    const int* __restrict__ mask,
    float* __restrict__ pctx, float2* __restrict__ pml)
{
    __shared__ short8 kbuf[2][4][64];
    __shared__ short8 vbuf[2][4][64];
    __shared__ unsigned pbuf[4][2][64][4];
    __shared__ float ry_s[16][68];
    __shared__ float mbuf[2][64];

    const int tid  = threadIdx.x;
    const int lane = tid & 63;
    const int w    = tid >> 6;
    const int q15  = lane & 15;
    const int g    = lane >> 4;
    const int qt = blockIdx.x, h = blockIdx.y;
    const int b  = blockIdx.z >> 2;
    const int sp = blockIdx.z & 3;
    const int q0 = qt * 64;
    const int wq = w * 16 + q15;
    const int gq = q0 + wq;
    const bool qok = gq < NQ;
    const int kv0g = sp * KVSEG;

    // rx bias -> 16 registers (x = 16*kt + 4*g + r, fixed per lane)
    float rxr[16];
    {
        const float* rxrow = RX + (size_t)(b * NQ + (qok ? gq : 0)) * (NHEAD * GRID) + h * GRID;
        #pragma unroll
        for (int kt = 0; kt < 4; ++kt)
            #pragma unroll
            for (int r = 0; r < 4; ++r)
                rxr[kt * 4 + r] = qok ? rxrow[16 * kt + 4 * g + r] : 0.f;
    }
    // ry tile for this split's 16 grid rows
    for (int idx = tid; idx < 16 * 64; idx += 256) {
        int y = idx & 15, q = idx >> 4;
        int gq2 = q0 + q;
        ry_s[y][q] = (gq2 < NQ)
            ? RY[(size_t)(b * NQ + gq2) * (NHEAD * GRID) + h * GRID + sp * 16 + y] : 0.f;
    }

    short8 qf = *(const short8*)(Qbf + ((size_t)(b * NQ + gq)) * DIMM + h * HD + 8 * g);

    const int sr = tid >> 2, sc = tid & 3;
    const int vd = tid >> 3, vc = tid & 7;
    const size_t kbase = ((size_t)(b * NKV + kv0g + sr)) * DIMM + h * HD + 8 * sc;
    const size_t vbase = ((size_t)((b * NHEAD + h) * HD + vd)) * NKV + kv0g + 8 * vc;

    kbuf[0][sr >> 4][(sr & 15) + 16 * sc] = *(const short8*)(Kbf + kbase);
    vbuf[0][(vc >> 2) * 2 + (vd >> 4)][16 * (vc & 3) + (vd & 15)] = *(const short8*)(Vt + vbase);
    if (tid < 64) mbuf[0][tid] = -100.f * (float)mask[b * NKV + kv0g + tid];
    __syncthreads();

    f32x4 cacc0 = {0.f, 0.f, 0.f, 0.f};
    f32x4 cacc1 = {0.f, 0.f, 0.f, 0.f};
    float m_run = -1e30f, l_run = 0.f;
    int cur = 0;

    for (int t = 0; t < NT; ++t) {
        short8 rk = {}, rv = {};
        float rm = 0.f;
        if (t < NT - 1) {
            size_t kvn = (size_t)(t + 1) * 64;
            rk = *(const short8*)(Kbf + kbase + kvn * DIMM);
            rv = *(const short8*)(Vt + vbase + kvn);
            if (tid < 64) rm = -100.f * (float)mask[b * NKV + kv0g + kvn + tid];
        }

        f32x4 zero = {0.f, 0.f, 0.f, 0.f};
        f32x4 s[4];
        __builtin_amdgcn_s_setprio(1);
        #pragma unroll
        for (int kt = 0; kt < 4; ++kt)
            s[kt] = __builtin_amdgcn_mfma_f32_16x16x32_bf16(kbuf[cur][kt][lane], qf, zero, 0, 0, 0);
        __builtin_amdgcn_s_setprio(0);

        float ryb = ry_s[t][wq];
        #pragma unroll
        for (int kt = 0; kt < 4; ++kt) {
            #pragma unroll
            for (int r = 0; r < 4; ++r)
                s[kt][r] += rxr[kt * 4 + r] + ryb + mbuf[cur][16 * kt + 4 * g + r];
        }

        float mloc = s[0][0];
        #pragma unroll
        for (int kt = 0; kt < 4; ++kt)
            #pragma unroll
            for (int r = 0; r < 4; ++r) mloc = fmaxf(mloc, s[kt][r]);
        mloc = fmaxf(mloc, __shfl_xor(mloc, 16));
        mloc = fmaxf(mloc, __shfl_xor(mloc, 32));
        float mnew = fmaxf(m_run, mloc);
        float fsc  = __expf(m_run - mnew);
        float psum = 0.f;
        #pragma unroll
        for (int kt = 0; kt < 4; ++kt)
            #pragma unroll
            for (int r = 0; r < 4; ++r) {
                float pv = __expf(s[kt][r] - mnew);
                s[kt][r] = pv;
                psum += pv;
            }
        psum += __shfl_xor(psum, 16);
        psum += __shfl_xor(psum, 32);
        l_run = l_run * fsc + psum;
        m_run = mnew;
        cacc0 *= fsc;
        cacc1 *= fsc;

        #pragma unroll
        for (int kt = 0; kt < 4; ++kt) {
            unsigned d0 = packbf2(s[kt][0], s[kt][1]);
            unsigned d1 = packbf2(s[kt][2], s[kt][3]);
            int lt = 16 * ((2 * kt + (g >> 1)) & 3) + q15;
            uint2v* dst = (uint2v*)&pbuf[w][kt >> 1][lt][2 * (g & 1)];
            *dst = (uint2v){d0, d1};
        }

        __builtin_amdgcn_s_setprio(1);
        #pragma unroll
        for (int sk = 0; sk < 2; ++sk) {
            short8 pf = *(const short8*)&pbuf[w][sk][lane][0];
            cacc0 = __builtin_amdgcn_mfma_f32_16x16x32_bf16(vbuf[cur][sk * 2 + 0][lane], pf, cacc0, 0, 0, 0);
            cacc1 = __builtin_amdgcn_mfma_f32_16x16x32_bf16(vbuf[cur][sk * 2 + 1][lane], pf, cacc1, 0, 0, 0);
        }
        __builtin_amdgcn_s_setprio(0);

        if (t < NT - 1) {
            kbuf[cur ^ 1][sr >> 4][(sr & 15) + 16 * sc] = rk;
            vbuf[cur ^ 1][(vc >> 2) * 2 + (vd >> 4)][16 * (vc & 3) + (vd & 15)] = rv;
            if (tid < 64) mbuf[cur ^ 1][tid] = rm;
        }
        __syncthreads();
        cur ^= 1;
    }

    // unnormalized partial write (rows < NQP always valid)
    size_t prow = (size_t)(sp * NB + b) * NQP + gq;
    float* pc = pctx + prow * DIMM + h * HD;
    #pragma unroll
    for (int r = 0; r < 4; ++r) {
        pc[4 * g + r]      = cacc0[r];
        pc[16 + 4 * g + r] = cacc1[r];
    }
    if (g == 0) {
        float2 v; v.x = m_run; v.y = l_run;
        pml[prow * NHEAD + h] = v;
    }
}

// ---------------------------------------------------------------------------
// Combine the 4 KV-split partials: out = sum(w_i*ctx_i)/sum(w_i*l_i).
// ---------------------------------------------------------------------------
__global__ __launch_bounds__(256) void attn_reduce(
    const float* __restrict__ pctx, const float2* __restrict__ pml,
    float* __restrict__ CTX)
{
    const int bq = blockIdx.x;           // 0..1799
    const int b = bq / NQ, q = bq - b * NQ;
    const int c = threadIdx.x;
    const int h = c >> 5;

    float m[SPLIT], l[SPLIT];
    #pragma unroll
    for (int sp = 0; sp < SPLIT; ++sp) {
        float2 v = pml[((size_t)(sp * NB + b) * NQP + q) * NHEAD + h];
        m[sp] = v.x; l[sp] = v.y;
    }
    float ms = fmaxf(fmaxf(m[0], m[1]), fmaxf(m[2], m[3]));
    float L = 0.f, acc = 0.f;
    #pragma unroll
    for (int sp = 0; sp < SPLIT; ++sp) {
        float wgt = __expf(m[sp] - ms);
        L   += wgt * l[sp];
        acc += wgt * pctx[((size_t)(sp * NB + b) * NQP + q) * DIMM + c];
    }
    CTX[(size_t)bq * DIMM + c] = acc / L;
}

// ---------------------------------------------------------------------------
// fp32 GEMM for the output projection (precision-critical final linear).
// ---------------------------------------------------------------------------
__global__ __launch_bounds__(256) void gemm_bias_f32(
    const float* __restrict__ A, const float* __restrict__ W,
    const float* __restrict__ bias, float* __restrict__ C,
    int M, int N, int K)
{
    __shared__ float As[32][33];
    __shared__ float Ws[32][33];
    const int t  = threadIdx.x;
    const int tr = t >> 4;
    const int tc = t & 15;
    const int brow = blockIdx.y * 32;
    const int bcol = blockIdx.x * 32;
    float acc00 = 0.f, acc01 = 0.f, acc10 = 0.f, acc11 = 0.f;

    for (int kt = 0; kt < K; kt += 32) {
        #pragma unroll
        for (int i = 0; i < 4; ++i) {
            int idx = t + i * 256;
            int r = idx >> 5, c = idx & 31;
            int gr = brow + r;
            As[r][c] = (gr < M) ? A[(size_t)gr * K + kt + c] : 0.f;
            Ws[r][c] = W[(size_t)(bcol + r) * K + kt + c];
        }
        __syncthreads();
        #pragma unroll 8
        for (int k = 0; k < 32; ++k) {
            float a0 = As[tr * 2][k], a1 = As[tr * 2 + 1][k];
            float w0 = Ws[tc * 2][k], w1 = Ws[tc * 2 + 1][k];
            acc00 += a0 * w0; acc01 += a0 * w1;
            acc10 += a1 * w0; acc11 += a1 * w1;
        }
        __syncthreads();
    }
    int gc0 = bcol + tc * 2, gc1 = gc0 + 1;
    int gr0 = brow + tr * 2, gr1 = gr0 + 1;
    if (gr0 < M) {
        C[(size_t)gr0 * N + gc0] = acc00 + bias[gc0];
        C[(size_t)gr0 * N + gc1] = acc01 + bias[gc1];
    }
    if (gr1 < M) {
        C[(size_t)gr1 * N + gc0] = acc10 + bias[gc0];
        C[(size_t)gr1 * N + gc1] = acc11 + bias[gc1];
    }
}

// ---------------------------------------------------------------------------
extern "C" void kernel_launch(void* const* d_in, const int* in_sizes, int n_in,
                              void* d_out, int out_size, void* d_ws, size_t ws_size,
                              hipStream_t stream)
{
    const float* hs   = (const float*)d_in[0];
    const float* rp   = (const float*)d_in[1];
    const float* kv   = (const float*)d_in[2];
    const int*   msk  = (const int*)d_in[4];
    const float* m1w1 = (const float*)d_in[5];
    const float* m1b1 = (const float*)d_in[6];
    const float* m1w2 = (const float*)d_in[7];
    const float* m2w1 = (const float*)d_in[8];
    const float* m2b1 = (const float*)d_in[9];
    const float* m2w2 = (const float*)d_in[10];
    const float* q_w  = (const float*)d_in[11];
    const float* q_b  = (const float*)d_in[12];
    const float* k_w  = (const float*)d_in[13];
    const float* k_b  = (const float*)d_in[14];
    const float* v_w  = (const float*)d_in[15];
    const float* v_b  = (const float*)d_in[16];
    const float* o_w  = (const float*)d_in[17];
    const float* o_b  = (const float*)d_in[18];
    float* out = (float*)d_out;

    char* p = (char*)d_ws;
    float* RX   = (float*)p; p += (size_t)NB * NQ * NHEAD * GRID * 4;
    float* RY   = (float*)p; p += (size_t)NB * NQ * NHEAD * GRID * 4;
    float* CTX  = (float*)p; p += (size_t)NB * NQ * DIMM * 4;
    u16*   Qbf  = (u16*)p;   p += (size_t)1920 * DIMM * 2;
    u16*   Kbf  = (u16*)p;   p += (size_t)NB * NKV * DIMM * 2;
    u16*   Vt   = (u16*)p;   p += (size_t)NB * NHEAD * HD * NKV * 2;

    // union region: {bf16 conv buffers} (conv..proj) / {attn partials} (attn..reduce)
    char* u = p;
    u16* hsbf = (u16*)u;
    u16* kvbf = hsbf + (size_t)1920 * DIMM;
    u16* qwbf = kvbf + (size_t)NB * NKV * DIMM;
    u16* kwbf = qwbf + (size_t)DIMM * DIMM;
    u16* vwbf = kwbf + (size_t)DIMM * DIMM;
    float*  pctx = (float*)u;
    float2* pml  = (float2*)(pctx + (size_t)SPLIT * NB * NQP * DIMM);

    const float scale = 0.17677669529663687f;  // 32^-0.5

    // 1) fp32 -> bf16 conversion
    conv_bf16<<<1024, 256, 0, stream>>>(hs, kv, q_w, k_w, v_w,
                                        hsbf, kvbf, qwbf, kwbf, vwbf);

    // 2) Q projection (bf16 MFMA, scale folded)
    proj_mfma<<<dim3(15, 2, 1), 256, 0, stream>>>(
        hsbf, qwbf, q_b, nullptr, nullptr, Qbf, nullptr, NB * NQ, scale);

    // 3) K + V projections fused (z=0 -> K row-major, z=1 -> V transposed)
    proj_mfma<<<dim3(64, 2, 2), 256, 0, stream>>>(
        kvbf, kwbf, k_b, vwbf, v_b, Kbf, Vt, NB * NKV, 1.f);

    // 4) RPE MLPs
    rpe_kernel<<<225, 256, 0, stream>>>(rp, m1w1, m1b1, m1w2,
                                        m2w1, m2b1, m2w2, RX, RY);

    // 5) MFMA attention, KV-split x4
    attn_mfma<<<dim3((NQ + 63) / 64, NHEAD, NB * SPLIT), 256, 0, stream>>>(
        Qbf, Kbf, Vt, RX, RY, msk, pctx, pml);

    // 6) combine partials
    attn_reduce<<<NB * NQ, 256, 0, stream>>>(pctx, pml, CTX);

    // 7) Output projection (fp32)
    gemm_bias_f32<<<dim3(DIMM / 32, (NB * NQ + 31) / 32), 256, 0, stream>>>(
        CTX, o_w, o_b, out, NB * NQ, DIMM, DIMM);
}

// Round 5
// 151.295 us; speedup vs baseline: 6.8929x; 1.0571x over previous
//
#include <hip/hip_runtime.h>
#include <math.h>

#define NB    2
#define NQ    900
#define NQP   960
#define NKV   4096
#define DIMM  256
#define NHEAD 8
#define HD    32
#define RPEH  512
#define GRID  64
#define SPLIT 4
#define KVSEG 1024
#define NT    16

typedef short short8 __attribute__((ext_vector_type(8)));
typedef float f32x4 __attribute__((ext_vector_type(4)));
typedef unsigned uint2v __attribute__((ext_vector_type(2)));
typedef unsigned short u16;
typedef unsigned short u16x4 __attribute__((ext_vector_type(4)));

__device__ inline u16 f2bf(float f) {
    unsigned u = __builtin_bit_cast(unsigned, f);
    u += 0x7fff + ((u >> 16) & 1);
    return (u16)(u >> 16);
}
__device__ inline unsigned packbf2(float a, float b) {
    unsigned ua = __builtin_bit_cast(unsigned, a);
    ua += 0x7fff + ((ua >> 16) & 1);
    unsigned ub = __builtin_bit_cast(unsigned, b);
    ub += 0x7fff + ((ub >> 16) & 1);
    return (ua >> 16) | (ub & 0xffff0000u);
}

// ---------------------------------------------------------------------------
// fp32 -> bf16 conversion prepass (hs, kv, q_w, k_w, v_w), one launch.
// ---------------------------------------------------------------------------
#define HS4  115200   // 1800*256/4
#define KV4  524288   // 8192*256/4
#define W4   16384    // 256*256/4
__global__ __launch_bounds__(256) void conv_bf16(
    const float* __restrict__ hs, const float* __restrict__ kv,
    const float* __restrict__ qw, const float* __restrict__ kw,
    const float* __restrict__ vw,
    u16* __restrict__ hsbf, u16* __restrict__ kvbf,
    u16* __restrict__ qwbf, u16* __restrict__ kwbf, u16* __restrict__ vwbf)
{
    const int total = HS4 + KV4 + 3 * W4;
    for (int g = blockIdx.x * 256 + threadIdx.x; g < total; g += gridDim.x * 256) {
        const float* s; u16* d; int off;
        if (g < HS4)                       { s = hs; d = hsbf; off = g; }
        else if (g < HS4 + KV4)            { s = kv; d = kvbf; off = g - HS4; }
        else if (g < HS4 + KV4 + W4)       { s = qw; d = qwbf; off = g - HS4 - KV4; }
        else if (g < HS4 + KV4 + 2 * W4)   { s = kw; d = kwbf; off = g - HS4 - KV4 - W4; }
        else                               { s = vw; d = vwbf; off = g - HS4 - KV4 - 2 * W4; }
        f32x4 v = *(const f32x4*)(s + (size_t)off * 4);
        *(u16x4*)(d + (size_t)off * 4) =
            (u16x4){f2bf(v[0]), f2bf(v[1]), f2bf(v[2]), f2bf(v[3])};
    }
}

// ---------------------------------------------------------------------------
// bf16 MFMA projection GEMM (unchanged, verified).
// ---------------------------------------------------------------------------
__global__ __launch_bounds__(256) void proj_mfma(
    const u16* __restrict__ A,
    const u16* __restrict__ W0, const float* __restrict__ B0,
    const u16* __restrict__ W1, const float* __restrict__ B1,
    u16* __restrict__ outRow, u16* __restrict__ outVt,
    int M, float scale)
{
    __shared__ u16 Abuf[2][4096];
    __shared__ u16 Bbuf[2][4096];

    const u16* W = W0; const float* bias = B0; bool vt = false;
    if (blockIdx.z == 1) { W = W1; bias = B1; vt = true; }

    const int t    = threadIdx.x;
    const int lane = t & 63;
    const int w    = t >> 6;
    const int wm   = w >> 1, wn = w & 1;
    const int m0   = blockIdx.x * 128;
    const int n0   = blockIdx.y * 128;

    const int r0 = t >> 2, c0 = t & 3;
    const int r1 = r0 + 64;
    const int s0 = r0 * 4 + (c0 ^ (r0 & 3));
    const int s1 = r1 * 4 + (c0 ^ (r1 & 3));
    const u16* Arow0 = A + (size_t)(m0 + r0) * DIMM + c0 * 8;
    const u16* Arow1 = A + (size_t)(m0 + r1) * DIMM + c0 * 8;
    const u16* Wrow0 = W + (size_t)(n0 + r0) * DIMM + c0 * 8;
    const u16* Wrow1 = W + (size_t)(n0 + r1) * DIMM + c0 * 8;

    const int fr = lane & 15, fkc = lane >> 4;
    int aslot[4], bslot[4];
    #pragma unroll
    for (int f = 0; f < 4; ++f) {
        int ar = wm * 64 + f * 16 + fr;
        int br = wn * 64 + f * 16 + fr;
        aslot[f] = ar * 4 + (fkc ^ (ar & 3));
        bslot[f] = br * 4 + (fkc ^ (br & 3));
    }
    float bv[4];
    #pragma unroll
    for (int f = 0; f < 4; ++f) bv[f] = bias[n0 + wn * 64 + f * 16 + fr];

    f32x4 acc[4][4] = {};

    {
        short8 a0 = *(const short8*)(Arow0);
        short8 a1 = *(const short8*)(Arow1);
        short8 b0 = *(const short8*)(Wrow0);
        short8 b1 = *(const short8*)(Wrow1);
        *(short8*)&Abuf[0][s0 * 8] = a0;
        *(short8*)&Abuf[0][s1 * 8] = a1;
        *(short8*)&Bbuf[0][s0 * 8] = b0;
        *(short8*)&Bbuf[0][s1 * 8] = b1;
    }
    __syncthreads();

    int cur = 0;
    for (int kt = 0; kt < 8; ++kt) {
        short8 na0, na1, nb0, nb1;
        if (kt < 7) {
            int ko = (kt + 1) * 32;
            na0 = *(const short8*)(Arow0 + ko);
            na1 = *(const short8*)(Arow1 + ko);
            nb0 = *(const short8*)(Wrow0 + ko);
            nb1 = *(const short8*)(Wrow1 + ko);
        }
        short8 af[4], bf[4];
        #pragma unroll
        for (int f = 0; f < 4; ++f) {
            af[f] = *(const short8*)&Abuf[cur][aslot[f] * 8];
            bf[f] = *(const short8*)&Bbuf[cur][bslot[f] * 8];
        }
        #pragma unroll
        for (int i = 0; i < 4; ++i)
            #pragma unroll
            for (int j = 0; j < 4; ++j)
                acc[i][j] = __builtin_amdgcn_mfma_f32_16x16x32_bf16(af[i], bf[j], acc[i][j], 0, 0, 0);
        if (kt < 7) {
            *(short8*)&Abuf[cur ^ 1][s0 * 8] = na0;
            *(short8*)&Abuf[cur ^ 1][s1 * 8] = na1;
            *(short8*)&Bbuf[cur ^ 1][s0 * 8] = nb0;
            *(short8*)&Bbuf[cur ^ 1][s1 * 8] = nb1;
        }
        __syncthreads();
        cur ^= 1;
    }

    #pragma unroll
    for (int i = 0; i < 4; ++i) {
        int mbase = m0 + wm * 64 + i * 16 + 4 * fkc;
        #pragma unroll
        for (int j = 0; j < 4; ++j) {
            int n = n0 + wn * 64 + j * 16 + fr;
            #pragma unroll
            for (int r = 0; r < 4; ++r) {
                int gm = mbase + r;
                if (gm < M) {
                    float v = (acc[i][j][r] + bv[j]) * scale;
                    if (!vt) {
                        outRow[(size_t)gm * DIMM + n] = f2bf(v);
                    } else {
                        int bb = gm >> 12, kvi = gm & 4095;
                        int hh = n >> 5, dd = n & 31;
                        outVt[(size_t)((bb * NHEAD + hh) * HD + dd) * NKV + kvi] = f2bf(v);
                    }
                }
            }
        }
    }
}

// ---------------------------------------------------------------------------
// RPE MLPs. m-pure blocks: block bi handles mlp (bi&1), bq group (bi>>1)*4.
// Wave = one (bq, m) task over all 512 hidden. Stages only its own MLP's
// weights (24 KB LDS -> 6 blocks/CU). All weight reads are broadcasts.
// ---------------------------------------------------------------------------
__global__ __launch_bounds__(256) void rpe_kernel(
    const float* __restrict__ ref_pts,
    const float* __restrict__ w1x, const float* __restrict__ b1x,
    const float* __restrict__ w2x,
    const float* __restrict__ w1y, const float* __restrict__ b1y,
    const float* __restrict__ w2y,
    float* __restrict__ rpex, float* __restrict__ rpey)
{
    __shared__ f32x4 wpk[RPEH];            // {a, b, bias, a+b}
    __shared__ float w2t[RPEH][NHEAD];     // transposed second layer

    const int t = threadIdx.x;
    const int m = blockIdx.x & 1;
    const int bq0 = (blockIdx.x >> 1) * 4;

    const float* w1 = m ? w1y : w1x;
    const float* b1 = m ? b1y : b1x;
    const float* w2 = m ? w2y : w2x;
    for (int r = t; r < RPEH; r += 256) {
        float a = w1[r * 2], b = w1[r * 2 + 1];
        wpk[r] = (f32x4){a, b, b1[r], a + b};
    }
    for (int i = t; i < RPEH * NHEAD; i += 256) {
        int h = i >> 9, r = i & 511;
        w2t[r][h] = w2[h * RPEH + r];
    }
    __syncthreads();

    const int lane = t & 63;
    const int w    = t >> 6;
    const int bq   = bq0 + w;
    const float p  = (lane + 0.5f) * 16.f;

    const float* q = ref_pts + (size_t)bq * 4;
    const float c = m ? q[1] : q[0];
    const float s = m ? q[3] : q[2];
    const float lo = (c - s * 0.5f) * 1024.f;
    const float hi = (c + s * 0.5f) * 1024.f;

    float acc[8] = {};
    #pragma unroll 4
    for (int r = 0; r < RPEH; ++r) {
        f32x4 W  = wpk[r];
        f32x4 u0 = *(const f32x4*)&w2t[r][0];
        f32x4 u1 = *(const f32x4*)&w2t[r][4];
        float al  = W[0] * lo + W[1] * hi + W[2];
        float hid = fmaxf(al - W[3] * p, 0.f);
        acc[0] += u0[0] * hid;
        acc[1] += u0[1] * hid;
        acc[2] += u0[2] * hid;
        acc[3] += u0[3] * hid;
        acc[4] += u1[0] * hid;
        acc[5] += u1[1] * hid;
        acc[6] += u1[2] * hid;
        acc[7] += u1[3] * hid;
    }

    float* outp = m ? rpey : rpex;
    size_t base = (size_t)bq * (NHEAD * GRID) + lane;
    #pragma unroll
    for (int h = 0; h < 8; ++h) outp[base + h * GRID] = acc[h];
}

// ---------------------------------------------------------------------------
// MFMA attention, KV-split flash-decode (unchanged, verified).
// ---------------------------------------------------------------------------
__global__ __launch_bounds__(256) void attn_mfma(
    const u16* __restrict__ Qbf, const u16* __restrict__ Kbf,
    const u16* __restrict__ Vt,
    const float* __restrict__ RX, const float* __restrict__ RY,
    const int* __restrict__ mask,
    float* __restrict__ pctx, float2* __restrict__ pml)
{
    __shared__ short8 kbuf[2][4][64];
    __shared__ short8 vbuf[2][4][64];
    __shared__ unsigned pbuf[4][2][64][4];
    __shared__ float ry_s[16][68];
    __shared__ float mbuf[2][64];

    const int tid  = threadIdx.x;
    const int lane = tid & 63;
    const int w    = tid >> 6;
    const int q15  = lane & 15;
    const int g    = lane >> 4;
    const int qt = blockIdx.x, h = blockIdx.y;
    const int b  = blockIdx.z >> 2;
    const int sp = blockIdx.z & 3;
    const int q0 = qt * 64;
    const int wq = w * 16 + q15;
    const int gq = q0 + wq;
    const bool qok = gq < NQ;
    const int kv0g = sp * KVSEG;

    float rxr[16];
    {
        const float* rxrow = RX + (size_t)(b * NQ + (qok ? gq : 0)) * (NHEAD * GRID) + h * GRID;
        #pragma unroll
        for (int kt = 0; kt < 4; ++kt)
            #pragma unroll
            for (int r = 0; r < 4; ++r)
                rxr[kt * 4 + r] = qok ? rxrow[16 * kt + 4 * g + r] : 0.f;
    }
    for (int idx = tid; idx < 16 * 64; idx += 256) {
        int y = idx & 15, q = idx >> 4;
        int gq2 = q0 + q;
        ry_s[y][q] = (gq2 < NQ)
            ? RY[(size_t)(b * NQ + gq2) * (NHEAD * GRID) + h * GRID + sp * 16 + y] : 0.f;
    }

    short8 qf = *(const short8*)(Qbf + ((size_t)(b * NQ + gq)) * DIMM + h * HD + 8 * g);

    const int sr = tid >> 2, sc = tid & 3;
    const int vd = tid >> 3, vc = tid & 7;
    const size_t kbase = ((size_t)(b * NKV + kv0g + sr)) * DIMM + h * HD + 8 * sc;
    const size_t vbase = ((size_t)((b * NHEAD + h) * HD + vd)) * NKV + kv0g + 8 * vc;

    kbuf[0][sr >> 4][(sr & 15) + 16 * sc] = *(const short8*)(Kbf + kbase);
    vbuf[0][(vc >> 2) * 2 + (vd >> 4)][16 * (vc & 3) + (vd & 15)] = *(const short8*)(Vt + vbase);
    if (tid < 64) mbuf[0][tid] = -100.f * (float)mask[b * NKV + kv0g + tid];
    __syncthreads();

    f32x4 cacc0 = {0.f, 0.f, 0.f, 0.f};
    f32x4 cacc1 = {0.f, 0.f, 0.f, 0.f};
    float m_run = -1e30f, l_run = 0.f;
    int cur = 0;

    for (int t = 0; t < NT; ++t) {
        short8 rk = {}, rv = {};
        float rm = 0.f;
        if (t < NT - 1) {
            size_t kvn = (size_t)(t + 1) * 64;
            rk = *(const short8*)(Kbf + kbase + kvn * DIMM);
            rv = *(const short8*)(Vt + vbase + kvn);
            if (tid < 64) rm = -100.f * (float)mask[b * NKV + kv0g + kvn + tid];
        }

        f32x4 zero = {0.f, 0.f, 0.f, 0.f};
        f32x4 s[4];
        __builtin_amdgcn_s_setprio(1);
        #pragma unroll
        for (int kt = 0; kt < 4; ++kt)
            s[kt] = __builtin_amdgcn_mfma_f32_16x16x32_bf16(kbuf[cur][kt][lane], qf, zero, 0, 0, 0);
        __builtin_amdgcn_s_setprio(0);

        float ryb = ry_s[t][wq];
        #pragma unroll
        for (int kt = 0; kt < 4; ++kt) {
            #pragma unroll
            for (int r = 0; r < 4; ++r)
                s[kt][r] += rxr[kt * 4 + r] + ryb + mbuf[cur][16 * kt + 4 * g + r];
        }

        float mloc = s[0][0];
        #pragma unroll
        for (int kt = 0; kt < 4; ++kt)
            #pragma unroll
            for (int r = 0; r < 4; ++r) mloc = fmaxf(mloc, s[kt][r]);
        mloc = fmaxf(mloc, __shfl_xor(mloc, 16));
        mloc = fmaxf(mloc, __shfl_xor(mloc, 32));
        float mnew = fmaxf(m_run, mloc);
        float fsc  = __expf(m_run - mnew);
        float psum = 0.f;
        #pragma unroll
        for (int kt = 0; kt < 4; ++kt)
            #pragma unroll
            for (int r = 0; r < 4; ++r) {
                float pv = __expf(s[kt][r] - mnew);
                s[kt][r] = pv;
                psum += pv;
            }
        psum += __shfl_xor(psum, 16);
        psum += __shfl_xor(psum, 32);
        l_run = l_run * fsc + psum;
        m_run = mnew;
        cacc0 *= fsc;
        cacc1 *= fsc;

        #pragma unroll
        for (int kt = 0; kt < 4; ++kt) {
            unsigned d0 = packbf2(s[kt][0], s[kt][1]);
            unsigned d1 = packbf2(s[kt][2], s[kt][3]);
            int lt = 16 * ((2 * kt + (g >> 1)) & 3) + q15;
            uint2v* dst = (uint2v*)&pbuf[w][kt >> 1][lt][2 * (g & 1)];
            *dst = (uint2v){d0, d1};
        }

        __builtin_amdgcn_s_setprio(1);
        #pragma unroll
        for (int sk = 0; sk < 2; ++sk) {
            short8 pf = *(const short8*)&pbuf[w][sk][lane][0];
            cacc0 = __builtin_amdgcn_mfma_f32_16x16x32_bf16(vbuf[cur][sk * 2 + 0][lane], pf, cacc0, 0, 0, 0);
            cacc1 = __builtin_amdgcn_mfma_f32_16x16x32_bf16(vbuf[cur][sk * 2 + 1][lane], pf, cacc1, 0, 0, 0);
        }
        __builtin_amdgcn_s_setprio(0);

        if (t < NT - 1) {
            kbuf[cur ^ 1][sr >> 4][(sr & 15) + 16 * sc] = rk;
            vbuf[cur ^ 1][(vc >> 2) * 2 + (vd >> 4)][16 * (vc & 3) + (vd & 15)] = rv;
            if (tid < 64) mbuf[cur ^ 1][tid] = rm;
        }
        __syncthreads();
        cur ^= 1;
    }

    size_t prow = (size_t)(sp * NB + b) * NQP + gq;
    float* pc = pctx + prow * DIMM + h * HD;
    #pragma unroll
    for (int r = 0; r < 4; ++r) {
        pc[4 * g + r]      = cacc0[r];
        pc[16 + 4 * g + r] = cacc1[r];
    }
    if (g == 0) {
        float2 v; v.x = m_run; v.y = l_run;
        pml[prow * NHEAD + h] = v;
    }
}

// ---------------------------------------------------------------------------
// Combine the 4 KV-split partials (unchanged, verified).
// ---------------------------------------------------------------------------
__global__ __launch_bounds__(256) void attn_reduce(
    const float* __restrict__ pctx, const float2* __restrict__ pml,
    float* __restrict__ CTX)
{
    const int bq = blockIdx.x;
    const int b = bq / NQ, q = bq - b * NQ;
    const int c = threadIdx.x;
    const int h = c >> 5;

    float m[SPLIT], l[SPLIT];
    #pragma unroll
    for (int sp = 0; sp < SPLIT; ++sp) {
        float2 v = pml[((size_t)(sp * NB + b) * NQP + q) * NHEAD + h];
        m[sp] = v.x; l[sp] = v.y;
    }
    float ms = fmaxf(fmaxf(m[0], m[1]), fmaxf(m[2], m[3]));
    float L = 0.f, acc = 0.f;
    #pragma unroll
    for (int sp = 0; sp < SPLIT; ++sp) {
        float wgt = __expf(m[sp] - ms);
        L   += wgt * l[sp];
        acc += wgt * pctx[((size_t)(sp * NB + b) * NQP + q) * DIMM + c];
    }
    CTX[(size_t)bq * DIMM + c] = acc / L;
}

// ---------------------------------------------------------------------------
// fp32 GEMM for the output projection (unchanged, verified).
// ---------------------------------------------------------------------------
__global__ __launch_bounds__(256) void gemm_bias_f32(
    const float* __restrict__ A, const float* __restrict__ W,
    const float* __restrict__ bias, float* __restrict__ C,
    int M, int N, int K)
{
    __shared__ float As[32][33];
    __shared__ float Ws[32][33];
    const int t  = threadIdx.x;
    const int tr = t >> 4;
    const int tc = t & 15;
    const int brow = blockIdx.y * 32;
    const int bcol = blockIdx.x * 32;
    float acc00 = 0.f, acc01 = 0.f, acc10 = 0.f, acc11 = 0.f;

    for (int kt = 0; kt < K; kt += 32) {
        #pragma unroll
        for (int i = 0; i < 4; ++i) {
            int idx = t + i * 256;
            int r = idx >> 5, c = idx & 31;
            int gr = brow + r;
            As[r][c] = (gr < M) ? A[(size_t)gr * K + kt + c] : 0.f;
            Ws[r][c] = W[(size_t)(bcol + r) * K + kt + c];
        }
        __syncthreads();
        #pragma unroll 8
        for (int k = 0; k < 32; ++k) {
            float a0 = As[tr * 2][k], a1 = As[tr * 2 + 1][k];
            float w0 = Ws[tc * 2][k], w1 = Ws[tc * 2 + 1][k];
            acc00 += a0 * w0; acc01 += a0 * w1;
            acc10 += a1 * w0; acc11 += a1 * w1;
        }
        __syncthreads();
    }
    int gc0 = bcol + tc * 2, gc1 = gc0 + 1;
    int gr0 = brow + tr * 2, gr1 = gr0 + 1;
    if (gr0 < M) {
        C[(size_t)gr0 * N + gc0] = acc00 + bias[gc0];
        C[(size_t)gr0 * N + gc1] = acc01 + bias[gc1];
    }
    if (gr1 < M) {
        C[(size_t)gr1 * N + gc0] = acc10 + bias[gc0];
        C[(size_t)gr1 * N + gc1] = acc11 + bias[gc1];
    }
}

// ---------------------------------------------------------------------------
extern "C" void kernel_launch(void* const* d_in, const int* in_sizes, int n_in,
                              void* d_out, int out_size, void* d_ws, size_t ws_size,
                              hipStream_t stream)
{
    const float* hs   = (const float*)d_in[0];
    const float* rp   = (const float*)d_in[1];
    const float* kv   = (const float*)d_in[2];
    const int*   msk  = (const int*)d_in[4];
    const float* m1w1 = (const float*)d_in[5];
    const float* m1b1 = (const float*)d_in[6];
    const float* m1w2 = (const float*)d_in[7];
    const float* m2w1 = (const float*)d_in[8];
    const float* m2b1 = (const float*)d_in[9];
    const float* m2w2 = (const float*)d_in[10];
    const float* q_w  = (const float*)d_in[11];
    const float* q_b  = (const float*)d_in[12];
    const float* k_w  = (const float*)d_in[13];
    const float* k_b  = (const float*)d_in[14];
    const float* v_w  = (const float*)d_in[15];
    const float* v_b  = (const float*)d_in[16];
    const float* o_w  = (const float*)d_in[17];
    const float* o_b  = (const float*)d_in[18];
    float* out = (float*)d_out;

    char* p = (char*)d_ws;
    float* RX   = (float*)p; p += (size_t)NB * NQ * NHEAD * GRID * 4;
    float* RY   = (float*)p; p += (size_t)NB * NQ * NHEAD * GRID * 4;
    float* CTX  = (float*)p; p += (size_t)NB * NQ * DIMM * 4;
    u16*   Qbf  = (u16*)p;   p += (size_t)1920 * DIMM * 2;
    u16*   Kbf  = (u16*)p;   p += (size_t)NB * NKV * DIMM * 2;
    u16*   Vt   = (u16*)p;   p += (size_t)NB * NHEAD * HD * NKV * 2;

    // union region: {bf16 conv buffers} (conv..proj) / {attn partials} (attn..reduce)
    char* u = p;
    u16* hsbf = (u16*)u;
    u16* kvbf = hsbf + (size_t)1920 * DIMM;
    u16* qwbf = kvbf + (size_t)NB * NKV * DIMM;
    u16* kwbf = qwbf + (size_t)DIMM * DIMM;
    u16* vwbf = kwbf + (size_t)DIMM * DIMM;
    float*  pctx = (float*)u;
    float2* pml  = (float2*)(pctx + (size_t)SPLIT * NB * NQP * DIMM);

    const float scale = 0.17677669529663687f;  // 32^-0.5

    // 1) fp32 -> bf16 conversion
    conv_bf16<<<1024, 256, 0, stream>>>(hs, kv, q_w, k_w, v_w,
                                        hsbf, kvbf, qwbf, kwbf, vwbf);

    // 2) Q projection (bf16 MFMA, scale folded)
    proj_mfma<<<dim3(15, 2, 1), 256, 0, stream>>>(
        hsbf, qwbf, q_b, nullptr, nullptr, Qbf, nullptr, NB * NQ, scale);

    // 3) K + V projections fused (z=0 -> K row-major, z=1 -> V transposed)
    proj_mfma<<<dim3(64, 2, 2), 256, 0, stream>>>(
        kvbf, kwbf, k_b, vwbf, v_b, Kbf, Vt, NB * NKV, 1.f);

    // 4) RPE MLPs (900 m-pure blocks, wave = one (bq,m) task)
    rpe_kernel<<<900, 256, 0, stream>>>(rp, m1w1, m1b1, m1w2,
                                        m2w1, m2b1, m2w2, RX, RY);

    // 5) MFMA attention, KV-split x4
    attn_mfma<<<dim3((NQ + 63) / 64, NHEAD, NB * SPLIT), 256, 0, stream>>>(
        Qbf, Kbf, Vt, RX, RY, msk, pctx, pml);

    // 6) combine partials
    attn_reduce<<<NB * NQ, 256, 0, stream>>>(pctx, pml, CTX);

    // 7) Output projection (fp32)
    gemm_bias_f32<<<dim3(DIMM / 32, (NB * NQ + 31) / 32), 256, 0, stream>>>(
        CTX, o_w, o_b, out, NB * NQ, DIMM, DIMM);
}